// Round 9
// baseline (354.187 us; speedup 1.0000x reference)
//
#include <hip/hip_runtime.h>
#include <hip/hip_fp16.h>
#include <math.h>

#define LEAKY 0.2f

__device__ inline int h2i(__half2 h) { union { __half2 h; int i; } u; u.h = h; return u.i; }
__device__ inline __half2 i2h(int i) { union { __half2 h; int i; } u; u.i = i; return u.h; }

// ====== k_pre: hybrid histogram (blocks < HB) + GEMM1 (blocks >= HB) ======
// GEMM1: h1 = x @ W1 (N x 128 @ 128 x 128), fp16 h1 out, fused att dots.
__global__ __launch_bounds__(256) void k_pre(
    const float* __restrict__ x, const float* __restrict__ W,
    const float* __restrict__ att_s, const float* __restrict__ att_d,
    const int* __restrict__ ei, int* __restrict__ deg,
    unsigned* __restrict__ h1h, float* __restrict__ a1s, float* __restrict__ a1d,
    int N, int E, int Etot, int HB)
{
  __shared__ unsigned Wlh[128][64];   // half2-packed cols, 32KB
  __shared__ float Xl[64][128];       // 32KB
  int t = threadIdx.x;
  if ((int)blockIdx.x < HB) {
    int tid = blockIdx.x * 256 + t;
    for (int i = tid; i < Etot; i += HB * 256) {
      int d = (i < E) ? ei[E + i] : i - E;
      atomicAdd(&deg[d], 1);
    }
    return;
  }
  const float4* W4 = (const float4*)W;
#pragma unroll
  for (int i = 0; i < 16; ++i) {
    int id = t + i * 256;
    float4 wv = W4[id];
    Wlh[id >> 5][(id & 31) * 2]     = (unsigned)h2i(__floats2half2_rn(wv.x, wv.y));
    Wlh[id >> 5][(id & 31) * 2 + 1] = (unsigned)h2i(__floats2half2_rn(wv.z, wv.w));
  }
  int row0 = (blockIdx.x - HB) * 64;
  const float4* X4 = (const float4*)x;
  float4* Xl4 = (float4*)&Xl[0][0];
#pragma unroll
  for (int i = 0; i < 8; ++i) {
    int id = t + i * 256;
    int r = id >> 5, c = id & 31;
    int gr = row0 + r;
    Xl4[id] = (gr < N) ? X4[(size_t)gr * 32 + c] : make_float4(0.f, 0.f, 0.f, 0.f);
  }
  __syncthreads();
  int cg = t & 31, rg = t >> 5;
  float acc[8][4] = {};
#pragma unroll 2
  for (int k = 0; k < 128; k += 4) {
    float4 xv[8];
#pragma unroll
    for (int rr = 0; rr < 8; ++rr) xv[rr] = *(const float4*)&Xl[rg * 8 + rr][k];
#pragma unroll
    for (int kk = 0; kk < 4; ++kk) {
      uint2 wp = *(const uint2*)&Wlh[k + kk][cg * 2];
      float2 w01 = __half22float2(i2h((int)wp.x));
      float2 w23 = __half22float2(i2h((int)wp.y));
#pragma unroll
      for (int rr = 0; rr < 8; ++rr) {
        float xs = (&xv[rr].x)[kk];
        acc[rr][0] = fmaf(xs, w01.x, acc[rr][0]);
        acc[rr][1] = fmaf(xs, w01.y, acc[rr][1]);
        acc[rr][2] = fmaf(xs, w23.x, acc[rr][2]);
        acc[rr][3] = fmaf(xs, w23.y, acc[rr][3]);
      }
    }
  }
  int col = cg * 4;
  int h = (t >> 4) & 1;
  float4 asv = *(const float4*)&att_s[col];
  float4 adv = *(const float4*)&att_d[col];
#pragma unroll
  for (int rr = 0; rr < 8; ++rr) {
    int gr = row0 + rg * 8 + rr;
    float ps = acc[rr][0] * asv.x + acc[rr][1] * asv.y + acc[rr][2] * asv.z + acc[rr][3] * asv.w;
    float pd = acc[rr][0] * adv.x + acc[rr][1] * adv.y + acc[rr][2] * adv.z + acc[rr][3] * adv.w;
    ps += __shfl_xor(ps, 1); ps += __shfl_xor(ps, 2); ps += __shfl_xor(ps, 4); ps += __shfl_xor(ps, 8);
    pd += __shfl_xor(pd, 1); pd += __shfl_xor(pd, 2); pd += __shfl_xor(pd, 4); pd += __shfl_xor(pd, 8);
    if (gr < N) {
      unsigned p01 = (unsigned)h2i(__floats2half2_rn(acc[rr][0], acc[rr][1]));
      unsigned p23 = (unsigned)h2i(__floats2half2_rn(acc[rr][2], acc[rr][3]));
      *(uint2*)&h1h[(size_t)gr * 64 + cg * 2] = make_uint2(p01, p23);
      if ((t & 15) == 0) { a1s[gr * 2 + h] = ps; a1d[gr * 2 + h] = pd; }
    }
  }
}

// ====== k_scan: single-block exclusive scan of deg -> rowptr; also writes cursor ======
__global__ __launch_bounds__(1024) void k_scan(const int* deg, int* __restrict__ rowptr,
                                               int* cur, int N)
{
  __shared__ int ls[1024];
  int t = threadIdx.x;
  int CH = (N + 1024) / 1024;          // entries/thread, covers N+1 outputs
  int base = t * CH;
  int s = 0;
  for (int k = 0; k < CH; ++k) { int i = base + k; if (i < N) s += deg[i]; }
  ls[t] = s;
  __syncthreads();
  for (int off = 1; off < 1024; off <<= 1) {
    int v = (t >= off) ? ls[t - off] : 0;
    __syncthreads();
    ls[t] += v;
    __syncthreads();
  }
  int run = ls[t] - s;
  for (int k = 0; k < CH; ++k) {
    int i = base + k;
    if (i <= N) {
      rowptr[i] = run;
      if (i < N) { int d = deg[i]; cur[i] = run; run += d; }
    }
  }
}

__global__ __launch_bounds__(256) void k_scatter(const int* __restrict__ ei,
                                                 int* __restrict__ cur,
                                                 int* __restrict__ colx, int E, int Etot)
{
  int tid = blockIdx.x * 256 + threadIdx.x;
  if (tid >= Etot) return;
  int s, d;
  if (tid < E) { s = ei[tid]; d = ei[E + tid]; }
  else { s = d = tid - E; }
  int pos = atomicAdd(&cur[d], 1);
  colx[pos] = s;
}

// ====== Aggregate layer 1: TWO nodes per wave (32-lane halves, uint2 feats), 1 node-set/wave ======
__global__ __launch_bounds__(256) void k_agg1(
    const int* __restrict__ rowptr, const int* __restrict__ colx,
    const unsigned* __restrict__ h1h, const float* __restrict__ a1s,
    const float* __restrict__ a1d, const float* __restrict__ b1,
    unsigned* __restrict__ v1h, float* __restrict__ stats, int N)
{
  int t = threadIdx.x;
  int w = t >> 6, lane = t & 63;
  int g = lane >> 5, q = lane & 31;
  bool hi = q >= 16;                  // features 4q..4q+3 -> head = q>=16
  int n = blockIdx.x * 8 + w * 2 + g;
  bool act = n < N;
  float4 bias = *(const float4*)&b1[q * 4];
  int start = 0, end = 0;
  float2 ad = make_float2(0.f, 0.f);
  if (act) { start = rowptr[n]; end = rowptr[n + 1]; ad = *(const float2*)&a1d[n * 2]; }
  float se = 0.f;
  float4 acc = {0, 0, 0, 0};
  for (int base = start; base < end; base += 32) {
    int cnt = end - base; if (cnt > 32) cnt = 32;
    int sl = 0, epk = 0;
    if (q < cnt) {
      sl = colx[base + q];
      float2 av = *(const float2*)&a1s[sl * 2];
      float x0 = av.x + ad.x, x1 = av.y + ad.y;
      x0 = (x0 > 0.f) ? x0 : LEAKY * x0;
      x1 = (x1 > 0.f) ? x1 : LEAKY * x1;
      epk = h2i(__floats2half2_rn(__expf(x0), __expf(x1)));
    }
    int j = 0;
    int lim16 = cnt & ~15;
    for (; j < lim16; j += 16) {
      int ss[16], ee[16];
#pragma unroll
      for (int k = 0; k < 16; ++k) { ss[k] = __shfl(sl, j + k, 32); ee[k] = __shfl(epk, j + k, 32); }
      uint2 rr[16];
#pragma unroll
      for (int k = 0; k < 16; ++k) rr[k] = *(const uint2*)&h1h[(size_t)ss[k] * 64 + q * 2];
#pragma unroll
      for (int k = 0; k < 16; ++k) {
        float2 ef = __half22float2(i2h(ee[k]));
        float wg = hi ? ef.y : ef.x;
        float2 r01 = __half22float2(i2h((int)rr[k].x));
        float2 r23 = __half22float2(i2h((int)rr[k].y));
        se += wg;
        acc.x = fmaf(wg, r01.x, acc.x);
        acc.y = fmaf(wg, r01.y, acc.y);
        acc.z = fmaf(wg, r23.x, acc.z);
        acc.w = fmaf(wg, r23.y, acc.w);
      }
    }
    int lim8 = cnt & ~7;
    for (; j < lim8; j += 8) {
      int ss[8], ee[8];
#pragma unroll
      for (int k = 0; k < 8; ++k) { ss[k] = __shfl(sl, j + k, 32); ee[k] = __shfl(epk, j + k, 32); }
      uint2 rr[8];
#pragma unroll
      for (int k = 0; k < 8; ++k) rr[k] = *(const uint2*)&h1h[(size_t)ss[k] * 64 + q * 2];
#pragma unroll
      for (int k = 0; k < 8; ++k) {
        float2 ef = __half22float2(i2h(ee[k]));
        float wg = hi ? ef.y : ef.x;
        float2 r01 = __half22float2(i2h((int)rr[k].x));
        float2 r23 = __half22float2(i2h((int)rr[k].y));
        se += wg;
        acc.x = fmaf(wg, r01.x, acc.x);
        acc.y = fmaf(wg, r01.y, acc.y);
        acc.z = fmaf(wg, r23.x, acc.z);
        acc.w = fmaf(wg, r23.y, acc.w);
      }
    }
    for (; j < cnt; ++j) {
      int s0 = __shfl(sl, j, 32), e0 = __shfl(epk, j, 32);
      float2 ef = __half22float2(i2h(e0));
      float wg = hi ? ef.y : ef.x;
      uint2 rv = *(const uint2*)&h1h[(size_t)s0 * 64 + q * 2];
      float2 r01 = __half22float2(i2h((int)rv.x));
      float2 r23 = __half22float2(i2h((int)rv.y));
      se += wg;
      acc.x = fmaf(wg, r01.x, acc.x);
      acc.y = fmaf(wg, r01.y, acc.y);
      acc.z = fmaf(wg, r23.x, acc.z);
      acc.w = fmaf(wg, r23.y, acc.w);
    }
  }
  float4 o = {0, 0, 0, 0};
  if (act) {
    float inv = 1.f / se;
    o.x = fmaf(acc.x, inv, bias.x);
    o.y = fmaf(acc.y, inv, bias.y);
    o.z = fmaf(acc.z, inv, bias.z);
    o.w = fmaf(acc.w, inv, bias.w);
    unsigned p01 = (unsigned)h2i(__floats2half2_rn(o.x, o.y));
    unsigned p23 = (unsigned)h2i(__floats2half2_rn(o.z, o.w));
    *(uint2*)&v1h[(size_t)n * 64 + q * 2] = make_uint2(p01, p23);
  }
  __shared__ float4 reds[4][64], redq[4][64];
  reds[w][lane] = o;
  redq[w][lane] = make_float4(o.x * o.x, o.y * o.y, o.z * o.z, o.w * o.w);
  __syncthreads();
  if (t < 128) {
    int qq = t >> 2, ii = t & 3;
    float s = 0.f, sq = 0.f;
#pragma unroll
    for (int w2 = 0; w2 < 4; ++w2) {
      s  += (&reds[w2][qq].x)[ii] + (&reds[w2][qq + 32].x)[ii];
      sq += (&redq[w2][qq].x)[ii] + (&redq[w2][qq + 32].x)[ii];
    }
    int sl8 = (blockIdx.x & 7) * 256;
    atomicAdd(&stats[sl8 + t], s);
    atomicAdd(&stats[sl8 + 128 + t], sq);
  }
}

// ====== GEMM2: h2 = relu(bn(v1h)) @ W2 (N x 128 @ 128 x 64), 8-sliced stats, padded Xl ======
__global__ __launch_bounds__(256) void k_gemm2(
    const unsigned* __restrict__ v1h, const float* __restrict__ W2,
    const float* __restrict__ stats, const float* __restrict__ g1, const float* __restrict__ be1,
    const float* __restrict__ att_s, const float* __restrict__ att_d,
    unsigned* __restrict__ h2h, float* __restrict__ a2s, float* __restrict__ a2d,
    int N, float rcpN)
{
  __shared__ float Wl[128][64];
  __shared__ float Xl[64][132];
  __shared__ float kc[128], sc[128];
  int t = threadIdx.x;
  if (t < 128) {
    float su = 0.f, sq = 0.f;
#pragma unroll
    for (int s8 = 0; s8 < 8; ++s8) { su += stats[s8 * 256 + t]; sq += stats[s8 * 256 + 128 + t]; }
    float mu = su * rcpN;
    float var = sq * rcpN - mu * mu;
    float kk = g1[t] * rsqrtf(var + 1e-5f);
    kc[t] = kk; sc[t] = be1[t] - mu * kk;
  }
  const float4* W4 = (const float4*)W2;
  float4* Wl4 = (float4*)&Wl[0][0];
#pragma unroll
  for (int i = 0; i < 8; ++i) Wl4[t + i * 256] = W4[t + i * 256];
  __syncthreads();
  int row0 = blockIdx.x * 64;
#pragma unroll
  for (int i = 0; i < 8; ++i) {
    int id = t + i * 256;
    int r = id >> 5, c4 = id & 31;
    int gr = row0 + r;
    uint2 pv = (gr < N) ? *(const uint2*)&v1h[(size_t)gr * 64 + c4 * 2] : make_uint2(0, 0);
    float2 a01 = __half22float2(i2h((int)pv.x));
    float2 a23 = __half22float2(i2h((int)pv.y));
    int f0 = c4 * 4;
    float4 o;
    o.x = fmaxf(a01.x * kc[f0]     + sc[f0],     0.f);
    o.y = fmaxf(a01.y * kc[f0 + 1] + sc[f0 + 1], 0.f);
    o.z = fmaxf(a23.x * kc[f0 + 2] + sc[f0 + 2], 0.f);
    o.w = fmaxf(a23.y * kc[f0 + 3] + sc[f0 + 3], 0.f);
    *(float4*)&Xl[r][c4 * 4] = o;
  }
  __syncthreads();
  int cg = t & 15, rg = t >> 4;
  float acc[4][4] = {};
#pragma unroll 2
  for (int k = 0; k < 128; k += 4) {
    float4 xv[4];
#pragma unroll
    for (int rr = 0; rr < 4; ++rr) xv[rr] = *(const float4*)&Xl[rg * 4 + rr][k];
#pragma unroll
    for (int kk = 0; kk < 4; ++kk) {
      float4 wv = *(const float4*)&Wl[k + kk][cg * 4];
#pragma unroll
      for (int rr = 0; rr < 4; ++rr) {
        float xs = (&xv[rr].x)[kk];
        acc[rr][0] = fmaf(xs, wv.x, acc[rr][0]);
        acc[rr][1] = fmaf(xs, wv.y, acc[rr][1]);
        acc[rr][2] = fmaf(xs, wv.z, acc[rr][2]);
        acc[rr][3] = fmaf(xs, wv.w, acc[rr][3]);
      }
    }
  }
  int col = cg * 4;
  float4 asv = *(const float4*)&att_s[col];
  float4 adv = *(const float4*)&att_d[col];
#pragma unroll
  for (int rr = 0; rr < 4; ++rr) {
    int gr = row0 + rg * 4 + rr;
    float ps = acc[rr][0] * asv.x + acc[rr][1] * asv.y + acc[rr][2] * asv.z + acc[rr][3] * asv.w;
    float pd = acc[rr][0] * adv.x + acc[rr][1] * adv.y + acc[rr][2] * adv.z + acc[rr][3] * adv.w;
    ps += __shfl_xor(ps, 1); ps += __shfl_xor(ps, 2); ps += __shfl_xor(ps, 4); ps += __shfl_xor(ps, 8);
    pd += __shfl_xor(pd, 1); pd += __shfl_xor(pd, 2); pd += __shfl_xor(pd, 4); pd += __shfl_xor(pd, 8);
    if (gr < N) {
      unsigned p01 = (unsigned)h2i(__floats2half2_rn(acc[rr][0], acc[rr][1]));
      unsigned p23 = (unsigned)h2i(__floats2half2_rn(acc[rr][2], acc[rr][3]));
      *(uint2*)&h2h[(size_t)gr * 32 + cg * 2] = make_uint2(p01, p23);
      if ((t & 15) == 0) { a2s[gr] = ps; a2d[gr] = pd; }
    }
  }
}

// ====== Aggregate layer 2: FOUR nodes per wave (16-lane groups, 4 feats/lane via uint2) ======
__global__ __launch_bounds__(256) void k_agg2(
    const int* __restrict__ rowptr, const int* __restrict__ colx,
    const unsigned* __restrict__ h2h, const float* __restrict__ a2s,
    const float* __restrict__ a2d, const float* __restrict__ b2,
    unsigned* __restrict__ v2h, float* __restrict__ stats, int N)
{
  int t = threadIdx.x;
  int w = t >> 6, lane = t & 63;
  int g = lane >> 4, q = lane & 15;     // 4 node-groups x 16 lanes
  int n = blockIdx.x * 16 + w * 4 + g;
  bool act = n < N;
  float4 bias = *(const float4*)&b2[q * 4];
  int start = 0, end = 0;
  float ad = 0.f;
  if (act) { start = rowptr[n]; end = rowptr[n + 1]; ad = a2d[n]; }
  float se = 0.f;
  float4 acc = {0, 0, 0, 0};
  for (int base = start; base < end; base += 16) {
    int cnt = end - base; if (cnt > 16) cnt = 16;
    int sl = 0; float ev = 0.f;
    if (q < cnt) {
      sl = colx[base + q];
      float av = a2s[sl] + ad;
      av = (av > 0.f) ? av : LEAKY * av;
      ev = __expf(av);
    }
    int j = 0;
    if (cnt == 16) {
      int ss[16]; float ee[16];
#pragma unroll
      for (int k = 0; k < 16; ++k) { ss[k] = __shfl(sl, k, 16); ee[k] = __shfl(ev, k, 16); }
      uint2 rr[16];
#pragma unroll
      for (int k = 0; k < 16; ++k) rr[k] = *(const uint2*)&h2h[(size_t)ss[k] * 32 + q * 2];
#pragma unroll
      for (int k = 0; k < 16; ++k) {
        float2 r01 = __half22float2(i2h((int)rr[k].x));
        float2 r23 = __half22float2(i2h((int)rr[k].y));
        se += ee[k];
        acc.x = fmaf(ee[k], r01.x, acc.x);
        acc.y = fmaf(ee[k], r01.y, acc.y);
        acc.z = fmaf(ee[k], r23.x, acc.z);
        acc.w = fmaf(ee[k], r23.y, acc.w);
      }
      j = 16;
    }
    int lim8 = cnt & ~7;
    for (; j < lim8; j += 8) {
      int ss[8]; float ee[8];
#pragma unroll
      for (int k = 0; k < 8; ++k) { ss[k] = __shfl(sl, j + k, 16); ee[k] = __shfl(ev, j + k, 16); }
      uint2 rr[8];
#pragma unroll
      for (int k = 0; k < 8; ++k) rr[k] = *(const uint2*)&h2h[(size_t)ss[k] * 32 + q * 2];
#pragma unroll
      for (int k = 0; k < 8; ++k) {
        float2 r01 = __half22float2(i2h((int)rr[k].x));
        float2 r23 = __half22float2(i2h((int)rr[k].y));
        se += ee[k];
        acc.x = fmaf(ee[k], r01.x, acc.x);
        acc.y = fmaf(ee[k], r01.y, acc.y);
        acc.z = fmaf(ee[k], r23.x, acc.z);
        acc.w = fmaf(ee[k], r23.y, acc.w);
      }
    }
    for (; j < cnt; ++j) {
      int s0 = __shfl(sl, j, 16);
      float e0 = __shfl(ev, j, 16);
      uint2 rv = *(const uint2*)&h2h[(size_t)s0 * 32 + q * 2];
      float2 r01 = __half22float2(i2h((int)rv.x));
      float2 r23 = __half22float2(i2h((int)rv.y));
      se += e0;
      acc.x = fmaf(e0, r01.x, acc.x);
      acc.y = fmaf(e0, r01.y, acc.y);
      acc.z = fmaf(e0, r23.x, acc.z);
      acc.w = fmaf(e0, r23.y, acc.w);
    }
  }
  float4 o = {0, 0, 0, 0};
  if (act) {
    float inv = 1.f / se;
    o.x = fmaf(acc.x, inv, bias.x);
    o.y = fmaf(acc.y, inv, bias.y);
    o.z = fmaf(acc.z, inv, bias.z);
    o.w = fmaf(acc.w, inv, bias.w);
    unsigned p01 = (unsigned)h2i(__floats2half2_rn(o.x, o.y));
    unsigned p23 = (unsigned)h2i(__floats2half2_rn(o.z, o.w));
    *(uint2*)&v2h[(size_t)n * 32 + q * 2] = make_uint2(p01, p23);
  }
  __shared__ float4 reds[4][64], redq[4][64];
  reds[w][lane] = o;
  redq[w][lane] = make_float4(o.x * o.x, o.y * o.y, o.z * o.z, o.w * o.w);
  __syncthreads();
  if (t < 64) {
    int qq = t >> 2, ii = t & 3;
    float s = 0.f, sq = 0.f;
#pragma unroll
    for (int w2 = 0; w2 < 4; ++w2) {
#pragma unroll
      for (int g2 = 0; g2 < 4; ++g2) {
        s  += (&reds[w2][g2 * 16 + qq].x)[ii];
        sq += (&redq[w2][g2 * 16 + qq].x)[ii];
      }
    }
    int sl8 = (blockIdx.x & 7) * 128;
    atomicAdd(&stats[sl8 + t], s);
    atomicAdd(&stats[sl8 + 64 + t], sq);
  }
}

// ====== Final: out = relu(bn(v2h)) @ linW + linb, 2 nodes/wave, shared BN ======
__global__ __launch_bounds__(256) void k_out(
    const unsigned* __restrict__ v2h, const float* __restrict__ stats,
    const float* __restrict__ g2, const float* __restrict__ be2,
    const float* __restrict__ linW, const float* __restrict__ linb,
    float* __restrict__ out, int N, float rcpN)
{
  __shared__ float kc[64], sc[64], lw[64];
  int t = threadIdx.x;
  if (t < 64) {
    float su = 0.f, sq = 0.f;
#pragma unroll
    for (int s8 = 0; s8 < 8; ++s8) { su += stats[s8 * 128 + t]; sq += stats[s8 * 128 + 64 + t]; }
    float mu = su * rcpN;
    float var = sq * rcpN - mu * mu;
    float kk = g2[t] * rsqrtf(var + 1e-5f);
    kc[t] = kk; sc[t] = be2[t] - mu * kk; lw[t] = linW[t];
  }
  __syncthreads();
  int w = t >> 6, lane = t & 63, g = lane >> 5, q = lane & 31;
  int n = blockIdx.x * 8 + w * 2 + g;
  if (n >= N) return;
  unsigned uv = v2h[(size_t)n * 32 + q];
  float2 vf = __half22float2(i2h((int)uv));
  float h0 = fmaxf(vf.x * kc[2 * q] + sc[2 * q], 0.f);
  float h1 = fmaxf(vf.y * kc[2 * q + 1] + sc[2 * q + 1], 0.f);
  float p = fmaf(h0, lw[2 * q], h1 * lw[2 * q + 1]);
#pragma unroll
  for (int off = 16; off; off >>= 1) p += __shfl_xor(p, off, 32);
  if (q == 0) out[n] = p + linb[0];
}

extern "C" void kernel_launch(void* const* d_in, const int* in_sizes, int n_in,
                              void* d_out, int out_size, void* d_ws, size_t ws_size,
                              hipStream_t stream)
{
  const float* x    = (const float*)d_in[0];
  const int*   ei   = (const int*)d_in[1];
  const float* W1   = (const float*)d_in[2];
  const float* as1  = (const float*)d_in[3];
  const float* ad1  = (const float*)d_in[4];
  const float* b1   = (const float*)d_in[5];
  const float* g1   = (const float*)d_in[6];
  const float* be1  = (const float*)d_in[7];
  const float* W2   = (const float*)d_in[8];
  const float* as2  = (const float*)d_in[9];
  const float* ad2  = (const float*)d_in[10];
  const float* b2   = (const float*)d_in[11];
  const float* g2   = (const float*)d_in[12];
  const float* be2  = (const float*)d_in[13];
  const float* linW = (const float*)d_in[14];
  const float* linb = (const float*)d_in[15];
  float* out = (float*)d_out;

  int N = in_sizes[0] / 128;
  int E = in_sizes[1] / 2;
  int Etot = E + N;
  float rcpN = 1.f / (float)N;

  float* ws = (float*)d_ws;
  size_t o = 0;
  float* H1HF = ws + o; o += (size_t)N * 64;   // h1 fp16 (N x 128 halves); later h2h (N x 64 halves)
  float* V1HF = ws + o; o += (size_t)N * 64;   // v1 fp16; later v2h
  float* A1S  = ws + o; o += (size_t)N * 2;
  float* A1D  = ws + o; o += (size_t)N * 2;
  float* A2S  = ws + o; o += N;
  float* A2D  = ws + o; o += N;
  float* ST1  = ws + o; o += 8 * 256;          // 8-sliced layer-1 stats (zero region)
  float* ST2  = ws + o; o += 8 * 128;          // 8-sliced layer-2 stats
  int* ROWPTR = (int*)(ws + o); o += (size_t)N + 1;
  int* COL    = (int*)(ws + o); o += (size_t)Etot;
  int* DEG    = (int*)(ws + o); o += N;        // hist target, then scatter cursor
  unsigned* H1H = (unsigned*)H1HF;
  unsigned* H2H = (unsigned*)H1HF;             // h2h aliases dead h1 region
  unsigned* V1H = (unsigned*)V1HF;
  unsigned* V2H = (unsigned*)V1HF;             // v2h aliases dead v1 region

  hipMemsetAsync(ST1, 0, 3072 * 4, stream);
  hipMemsetAsync(DEG, 0, (size_t)N * 4, stream);

  const int HB = 256;
  int gb = (N + 63) / 64;
  int ebk = (Etot + 255) / 256;
  int ab1 = (N + 7) / 8;
  int ab2 = (N + 15) / 16;
  int ob  = (N + 7) / 8;

  k_pre<<<HB + gb, 256, 0, stream>>>(x, W1, as1, ad1, ei, DEG, H1H, A1S, A1D, N, E, Etot, HB);
  k_scan<<<1, 1024, 0, stream>>>(DEG, ROWPTR, DEG, N);
  k_scatter<<<ebk, 256, 0, stream>>>(ei, DEG, COL, E, Etot);
  k_agg1<<<ab1, 256, 0, stream>>>(ROWPTR, COL, H1H, A1S, A1D, b1, V1H, ST1, N);
  k_gemm2<<<gb, 256, 0, stream>>>(V1H, W2, ST1, g1, be1, as2, ad2, H2H, A2S, A2D, N, rcpN);
  k_agg2<<<ab2, 256, 0, stream>>>(ROWPTR, COL, H2H, A2S, A2D, b2, V2H, ST2, N);
  k_out<<<ob, 256, 0, stream>>>(V2H, ST2, g2, be2, linW, linb, out, N, rcpN);
}

// Round 10
// 245.477 us; speedup vs baseline: 1.4429x; 1.4429x over previous
//
#include <hip/hip_runtime.h>
#include <hip/hip_fp16.h>
#include <math.h>

#define LEAKY 0.2f

__device__ inline int h2i(__half2 h) { union { __half2 h; int i; } u; u.h = h; return u.i; }
__device__ inline __half2 i2h(int i) { union { __half2 h; int i; } u; u.i = i; return u.h; }

// ====== k_pre: hybrid histogram (blocks < HB) + GEMM1 (blocks >= HB) ======
// GEMM1: h1 = x @ W1 (N x 128 @ 128 x 128), fp16 h1 out, fused att dots.
__global__ __launch_bounds__(256) void k_pre(
    const float* __restrict__ x, const float* __restrict__ W,
    const float* __restrict__ att_s, const float* __restrict__ att_d,
    const int* __restrict__ ei, int* __restrict__ deg,
    unsigned* __restrict__ h1h, float* __restrict__ a1s, float* __restrict__ a1d,
    int N, int E, int Etot, int HB)
{
  __shared__ unsigned Wlh[128][64];   // half2-packed cols, 32KB
  __shared__ float Xl[64][128];       // 32KB
  int t = threadIdx.x;
  if ((int)blockIdx.x < HB) {
    int tid = blockIdx.x * 256 + t;
    for (int i = tid; i < Etot; i += HB * 256) {
      int d = (i < E) ? ei[E + i] : i - E;
      atomicAdd(&deg[d], 1);
    }
    return;
  }
  const float4* W4 = (const float4*)W;
#pragma unroll
  for (int i = 0; i < 16; ++i) {
    int id = t + i * 256;
    float4 wv = W4[id];
    Wlh[id >> 5][(id & 31) * 2]     = (unsigned)h2i(__floats2half2_rn(wv.x, wv.y));
    Wlh[id >> 5][(id & 31) * 2 + 1] = (unsigned)h2i(__floats2half2_rn(wv.z, wv.w));
  }
  int row0 = (blockIdx.x - HB) * 64;
  const float4* X4 = (const float4*)x;
  float4* Xl4 = (float4*)&Xl[0][0];
#pragma unroll
  for (int i = 0; i < 8; ++i) {
    int id = t + i * 256;
    int r = id >> 5, c = id & 31;
    int gr = row0 + r;
    Xl4[id] = (gr < N) ? X4[(size_t)gr * 32 + c] : make_float4(0.f, 0.f, 0.f, 0.f);
  }
  __syncthreads();
  int cg = t & 31, rg = t >> 5;
  float acc[8][4] = {};
#pragma unroll 2
  for (int k = 0; k < 128; k += 4) {
    float4 xv[8];
#pragma unroll
    for (int rr = 0; rr < 8; ++rr) xv[rr] = *(const float4*)&Xl[rg * 8 + rr][k];
#pragma unroll
    for (int kk = 0; kk < 4; ++kk) {
      uint2 wp = *(const uint2*)&Wlh[k + kk][cg * 2];
      float2 w01 = __half22float2(i2h((int)wp.x));
      float2 w23 = __half22float2(i2h((int)wp.y));
#pragma unroll
      for (int rr = 0; rr < 8; ++rr) {
        float xs = (&xv[rr].x)[kk];
        acc[rr][0] = fmaf(xs, w01.x, acc[rr][0]);
        acc[rr][1] = fmaf(xs, w01.y, acc[rr][1]);
        acc[rr][2] = fmaf(xs, w23.x, acc[rr][2]);
        acc[rr][3] = fmaf(xs, w23.y, acc[rr][3]);
      }
    }
  }
  int col = cg * 4;
  int h = (t >> 4) & 1;
  float4 asv = *(const float4*)&att_s[col];
  float4 adv = *(const float4*)&att_d[col];
#pragma unroll
  for (int rr = 0; rr < 8; ++rr) {
    int gr = row0 + rg * 8 + rr;
    float ps = acc[rr][0] * asv.x + acc[rr][1] * asv.y + acc[rr][2] * asv.z + acc[rr][3] * asv.w;
    float pd = acc[rr][0] * adv.x + acc[rr][1] * adv.y + acc[rr][2] * adv.z + acc[rr][3] * adv.w;
    ps += __shfl_xor(ps, 1); ps += __shfl_xor(ps, 2); ps += __shfl_xor(ps, 4); ps += __shfl_xor(ps, 8);
    pd += __shfl_xor(pd, 1); pd += __shfl_xor(pd, 2); pd += __shfl_xor(pd, 4); pd += __shfl_xor(pd, 8);
    if (gr < N) {
      unsigned p01 = (unsigned)h2i(__floats2half2_rn(acc[rr][0], acc[rr][1]));
      unsigned p23 = (unsigned)h2i(__floats2half2_rn(acc[rr][2], acc[rr][3]));
      *(uint2*)&h1h[(size_t)gr * 64 + cg * 2] = make_uint2(p01, p23);
      if ((t & 15) == 0) { a1s[gr * 2 + h] = ps; a1d[gr * 2 + h] = pd; }
    }
  }
}

// ====== multi-block scan: per-block scan -> partials; add_off folds partial-scan ======
__global__ __launch_bounds__(256) void k_scan_blk(const int* __restrict__ deg,
                                                  int* __restrict__ rowptr,
                                                  int* __restrict__ part, int N)
{
  __shared__ int ls[256];
  int t = threadIdx.x;
  int base = blockIdx.x * 1024 + t * 4;
  int d0 = (base     < N) ? deg[base]     : 0;
  int d1 = (base + 1 < N) ? deg[base + 1] : 0;
  int d2 = (base + 2 < N) ? deg[base + 2] : 0;
  int d3 = (base + 3 < N) ? deg[base + 3] : 0;
  int s = d0 + d1 + d2 + d3;
  ls[t] = s;
  __syncthreads();
  for (int off = 1; off < 256; off <<= 1) {
    int v = (t >= off) ? ls[t - off] : 0;
    __syncthreads();
    ls[t] += v;
    __syncthreads();
  }
  int excl = ls[t] - s;
  if (t == 255) part[blockIdx.x] = ls[255];
  if (base     <= N) rowptr[base]     = excl;
  if (base + 1 <= N) rowptr[base + 1] = excl + d0;
  if (base + 2 <= N) rowptr[base + 2] = excl + d0 + d1;
  if (base + 3 <= N) rowptr[base + 3] = excl + d0 + d1 + d2;
}

// add_off with the part-scan folded in (nb <= 64 required; N=50000 -> nb=49)
__global__ __launch_bounds__(256) void k_add_off(int* __restrict__ rowptr,
                                                 const int* __restrict__ part,
                                                 int* __restrict__ cur, int N, int nb)
{
  __shared__ int pexcl;
  int t = threadIdx.x;
  if (t < 64) {
    int v = (t < nb) ? part[t] : 0;
    int inc = v;
#pragma unroll
    for (int off = 1; off < 64; off <<= 1) {
      int u = __shfl_up(inc, off);
      if (t >= off) inc += u;
    }
    if (t == blockIdx.x) pexcl = inc - v;
  }
  __syncthreads();
  int p = pexcl;
  int base = blockIdx.x * 1024 + t * 4;
#pragma unroll
  for (int k = 0; k < 4; ++k) {
    int i = base + k;
    if (i <= N) {
      int v = rowptr[i] + p;
      rowptr[i] = v;
      if (i < N) cur[i] = v;
    }
  }
}

__global__ __launch_bounds__(256) void k_scatter(const int* __restrict__ ei,
                                                 int* __restrict__ cur,
                                                 int* __restrict__ colx, int E, int Etot)
{
  int tid = blockIdx.x * 256 + threadIdx.x;
  if (tid >= Etot) return;
  int s, d;
  if (tid < E) { s = ei[tid]; d = ei[E + tid]; }
  else { s = d = tid - E; }
  int pos = atomicAdd(&cur[d], 1);
  colx[pos] = s;
}

// ====== Aggregate layer 1: TWO nodes per wave (32-lane halves, uint2 feats), 1 node-set/wave ======
__global__ __launch_bounds__(256) void k_agg1(
    const int* __restrict__ rowptr, const int* __restrict__ colx,
    const unsigned* __restrict__ h1h, const float* __restrict__ a1s,
    const float* __restrict__ a1d, const float* __restrict__ b1,
    unsigned* __restrict__ v1h, float* __restrict__ stats, int N)
{
  int t = threadIdx.x;
  int w = t >> 6, lane = t & 63;
  int g = lane >> 5, q = lane & 31;
  bool hi = q >= 16;                  // features 4q..4q+3 -> head = q>=16
  int n = blockIdx.x * 8 + w * 2 + g;
  bool act = n < N;
  float4 bias = *(const float4*)&b1[q * 4];
  int start = 0, end = 0;
  float2 ad = make_float2(0.f, 0.f);
  if (act) { start = rowptr[n]; end = rowptr[n + 1]; ad = *(const float2*)&a1d[n * 2]; }
  float se = 0.f;
  float4 acc = {0, 0, 0, 0};
  for (int base = start; base < end; base += 32) {
    int cnt = end - base; if (cnt > 32) cnt = 32;
    int sl = 0, epk = 0;
    if (q < cnt) {
      sl = colx[base + q];
      float2 av = *(const float2*)&a1s[sl * 2];
      float x0 = av.x + ad.x, x1 = av.y + ad.y;
      x0 = (x0 > 0.f) ? x0 : LEAKY * x0;
      x1 = (x1 > 0.f) ? x1 : LEAKY * x1;
      epk = h2i(__floats2half2_rn(__expf(x0), __expf(x1)));
    }
    int j = 0;
    int lim16 = cnt & ~15;
    for (; j < lim16; j += 16) {
      int ss[16], ee[16];
#pragma unroll
      for (int k = 0; k < 16; ++k) { ss[k] = __shfl(sl, j + k, 32); ee[k] = __shfl(epk, j + k, 32); }
      uint2 rr[16];
#pragma unroll
      for (int k = 0; k < 16; ++k) rr[k] = *(const uint2*)&h1h[(size_t)ss[k] * 64 + q * 2];
#pragma unroll
      for (int k = 0; k < 16; ++k) {
        float2 ef = __half22float2(i2h(ee[k]));
        float wg = hi ? ef.y : ef.x;
        float2 r01 = __half22float2(i2h((int)rr[k].x));
        float2 r23 = __half22float2(i2h((int)rr[k].y));
        se += wg;
        acc.x = fmaf(wg, r01.x, acc.x);
        acc.y = fmaf(wg, r01.y, acc.y);
        acc.z = fmaf(wg, r23.x, acc.z);
        acc.w = fmaf(wg, r23.y, acc.w);
      }
    }
    int lim8 = cnt & ~7;
    for (; j < lim8; j += 8) {
      int ss[8], ee[8];
#pragma unroll
      for (int k = 0; k < 8; ++k) { ss[k] = __shfl(sl, j + k, 32); ee[k] = __shfl(epk, j + k, 32); }
      uint2 rr[8];
#pragma unroll
      for (int k = 0; k < 8; ++k) rr[k] = *(const uint2*)&h1h[(size_t)ss[k] * 64 + q * 2];
#pragma unroll
      for (int k = 0; k < 8; ++k) {
        float2 ef = __half22float2(i2h(ee[k]));
        float wg = hi ? ef.y : ef.x;
        float2 r01 = __half22float2(i2h((int)rr[k].x));
        float2 r23 = __half22float2(i2h((int)rr[k].y));
        se += wg;
        acc.x = fmaf(wg, r01.x, acc.x);
        acc.y = fmaf(wg, r01.y, acc.y);
        acc.z = fmaf(wg, r23.x, acc.z);
        acc.w = fmaf(wg, r23.y, acc.w);
      }
    }
    for (; j < cnt; ++j) {
      int s0 = __shfl(sl, j, 32), e0 = __shfl(epk, j, 32);
      float2 ef = __half22float2(i2h(e0));
      float wg = hi ? ef.y : ef.x;
      uint2 rv = *(const uint2*)&h1h[(size_t)s0 * 64 + q * 2];
      float2 r01 = __half22float2(i2h((int)rv.x));
      float2 r23 = __half22float2(i2h((int)rv.y));
      se += wg;
      acc.x = fmaf(wg, r01.x, acc.x);
      acc.y = fmaf(wg, r01.y, acc.y);
      acc.z = fmaf(wg, r23.x, acc.z);
      acc.w = fmaf(wg, r23.y, acc.w);
    }
  }
  float4 o = {0, 0, 0, 0};
  if (act) {
    float inv = 1.f / se;
    o.x = fmaf(acc.x, inv, bias.x);
    o.y = fmaf(acc.y, inv, bias.y);
    o.z = fmaf(acc.z, inv, bias.z);
    o.w = fmaf(acc.w, inv, bias.w);
    unsigned p01 = (unsigned)h2i(__floats2half2_rn(o.x, o.y));
    unsigned p23 = (unsigned)h2i(__floats2half2_rn(o.z, o.w));
    *(uint2*)&v1h[(size_t)n * 64 + q * 2] = make_uint2(p01, p23);
  }
  __shared__ float4 reds[4][64], redq[4][64];
  reds[w][lane] = o;
  redq[w][lane] = make_float4(o.x * o.x, o.y * o.y, o.z * o.z, o.w * o.w);
  __syncthreads();
  if (t < 128) {
    int qq = t >> 2, ii = t & 3;
    float s = 0.f, sq = 0.f;
#pragma unroll
    for (int w2 = 0; w2 < 4; ++w2) {
      s  += (&reds[w2][qq].x)[ii] + (&reds[w2][qq + 32].x)[ii];
      sq += (&redq[w2][qq].x)[ii] + (&redq[w2][qq + 32].x)[ii];
    }
    int sl8 = (blockIdx.x & 7) * 256;
    atomicAdd(&stats[sl8 + t], s);
    atomicAdd(&stats[sl8 + 128 + t], sq);
  }
}

// ====== GEMM2: h2 = relu(bn(v1h)) @ W2 (N x 128 @ 128 x 64), 8-sliced stats, padded Xl ======
__global__ __launch_bounds__(256) void k_gemm2(
    const unsigned* __restrict__ v1h, const float* __restrict__ W2,
    const float* __restrict__ stats, const float* __restrict__ g1, const float* __restrict__ be1,
    const float* __restrict__ att_s, const float* __restrict__ att_d,
    unsigned* __restrict__ h2h, float* __restrict__ a2s, float* __restrict__ a2d,
    int N, float rcpN)
{
  __shared__ float Wl[128][64];
  __shared__ float Xl[64][132];
  __shared__ float kc[128], sc[128];
  int t = threadIdx.x;
  if (t < 128) {
    float su = 0.f, sq = 0.f;
#pragma unroll
    for (int s8 = 0; s8 < 8; ++s8) { su += stats[s8 * 256 + t]; sq += stats[s8 * 256 + 128 + t]; }
    float mu = su * rcpN;
    float var = sq * rcpN - mu * mu;
    float kk = g1[t] * rsqrtf(var + 1e-5f);
    kc[t] = kk; sc[t] = be1[t] - mu * kk;
  }
  const float4* W4 = (const float4*)W2;
  float4* Wl4 = (float4*)&Wl[0][0];
#pragma unroll
  for (int i = 0; i < 8; ++i) Wl4[t + i * 256] = W4[t + i * 256];
  __syncthreads();
  int row0 = blockIdx.x * 64;
#pragma unroll
  for (int i = 0; i < 8; ++i) {
    int id = t + i * 256;
    int r = id >> 5, c4 = id & 31;
    int gr = row0 + r;
    uint2 pv = (gr < N) ? *(const uint2*)&v1h[(size_t)gr * 64 + c4 * 2] : make_uint2(0, 0);
    float2 a01 = __half22float2(i2h((int)pv.x));
    float2 a23 = __half22float2(i2h((int)pv.y));
    int f0 = c4 * 4;
    float4 o;
    o.x = fmaxf(a01.x * kc[f0]     + sc[f0],     0.f);
    o.y = fmaxf(a01.y * kc[f0 + 1] + sc[f0 + 1], 0.f);
    o.z = fmaxf(a23.x * kc[f0 + 2] + sc[f0 + 2], 0.f);
    o.w = fmaxf(a23.y * kc[f0 + 3] + sc[f0 + 3], 0.f);
    *(float4*)&Xl[r][c4 * 4] = o;
  }
  __syncthreads();
  int cg = t & 15, rg = t >> 4;
  float acc[4][4] = {};
#pragma unroll 2
  for (int k = 0; k < 128; k += 4) {
    float4 xv[4];
#pragma unroll
    for (int rr = 0; rr < 4; ++rr) xv[rr] = *(const float4*)&Xl[rg * 4 + rr][k];
#pragma unroll
    for (int kk = 0; kk < 4; ++kk) {
      float4 wv = *(const float4*)&Wl[k + kk][cg * 4];
#pragma unroll
      for (int rr = 0; rr < 4; ++rr) {
        float xs = (&xv[rr].x)[kk];
        acc[rr][0] = fmaf(xs, wv.x, acc[rr][0]);
        acc[rr][1] = fmaf(xs, wv.y, acc[rr][1]);
        acc[rr][2] = fmaf(xs, wv.z, acc[rr][2]);
        acc[rr][3] = fmaf(xs, wv.w, acc[rr][3]);
      }
    }
  }
  int col = cg * 4;
  float4 asv = *(const float4*)&att_s[col];
  float4 adv = *(const float4*)&att_d[col];
#pragma unroll
  for (int rr = 0; rr < 4; ++rr) {
    int gr = row0 + rg * 4 + rr;
    float ps = acc[rr][0] * asv.x + acc[rr][1] * asv.y + acc[rr][2] * asv.z + acc[rr][3] * asv.w;
    float pd = acc[rr][0] * adv.x + acc[rr][1] * adv.y + acc[rr][2] * adv.z + acc[rr][3] * adv.w;
    ps += __shfl_xor(ps, 1); ps += __shfl_xor(ps, 2); ps += __shfl_xor(ps, 4); ps += __shfl_xor(ps, 8);
    pd += __shfl_xor(pd, 1); pd += __shfl_xor(pd, 2); pd += __shfl_xor(pd, 4); pd += __shfl_xor(pd, 8);
    if (gr < N) {
      unsigned p01 = (unsigned)h2i(__floats2half2_rn(acc[rr][0], acc[rr][1]));
      unsigned p23 = (unsigned)h2i(__floats2half2_rn(acc[rr][2], acc[rr][3]));
      *(uint2*)&h2h[(size_t)gr * 32 + cg * 2] = make_uint2(p01, p23);
      if ((t & 15) == 0) { a2s[gr] = ps; a2d[gr] = pd; }
    }
  }
}

// ====== Aggregate layer 2: FOUR nodes per wave (16-lane groups, 4 feats/lane via uint2) ======
__global__ __launch_bounds__(256) void k_agg2(
    const int* __restrict__ rowptr, const int* __restrict__ colx,
    const unsigned* __restrict__ h2h, const float* __restrict__ a2s,
    const float* __restrict__ a2d, const float* __restrict__ b2,
    unsigned* __restrict__ v2h, float* __restrict__ stats, int N)
{
  int t = threadIdx.x;
  int w = t >> 6, lane = t & 63;
  int g = lane >> 4, q = lane & 15;     // 4 node-groups x 16 lanes
  int n = blockIdx.x * 16 + w * 4 + g;
  bool act = n < N;
  float4 bias = *(const float4*)&b2[q * 4];
  int start = 0, end = 0;
  float ad = 0.f;
  if (act) { start = rowptr[n]; end = rowptr[n + 1]; ad = a2d[n]; }
  float se = 0.f;
  float4 acc = {0, 0, 0, 0};
  for (int base = start; base < end; base += 16) {
    int cnt = end - base; if (cnt > 16) cnt = 16;
    int sl = 0; float ev = 0.f;
    if (q < cnt) {
      sl = colx[base + q];
      float av = a2s[sl] + ad;
      av = (av > 0.f) ? av : LEAKY * av;
      ev = __expf(av);
    }
    int j = 0;
    if (cnt == 16) {
      int ss[16]; float ee[16];
#pragma unroll
      for (int k = 0; k < 16; ++k) { ss[k] = __shfl(sl, k, 16); ee[k] = __shfl(ev, k, 16); }
      uint2 rr[16];
#pragma unroll
      for (int k = 0; k < 16; ++k) rr[k] = *(const uint2*)&h2h[(size_t)ss[k] * 32 + q * 2];
#pragma unroll
      for (int k = 0; k < 16; ++k) {
        float2 r01 = __half22float2(i2h((int)rr[k].x));
        float2 r23 = __half22float2(i2h((int)rr[k].y));
        se += ee[k];
        acc.x = fmaf(ee[k], r01.x, acc.x);
        acc.y = fmaf(ee[k], r01.y, acc.y);
        acc.z = fmaf(ee[k], r23.x, acc.z);
        acc.w = fmaf(ee[k], r23.y, acc.w);
      }
      j = 16;
    }
    int lim8 = cnt & ~7;
    for (; j < lim8; j += 8) {
      int ss[8]; float ee[8];
#pragma unroll
      for (int k = 0; k < 8; ++k) { ss[k] = __shfl(sl, j + k, 16); ee[k] = __shfl(ev, j + k, 16); }
      uint2 rr[8];
#pragma unroll
      for (int k = 0; k < 8; ++k) rr[k] = *(const uint2*)&h2h[(size_t)ss[k] * 32 + q * 2];
#pragma unroll
      for (int k = 0; k < 8; ++k) {
        float2 r01 = __half22float2(i2h((int)rr[k].x));
        float2 r23 = __half22float2(i2h((int)rr[k].y));
        se += ee[k];
        acc.x = fmaf(ee[k], r01.x, acc.x);
        acc.y = fmaf(ee[k], r01.y, acc.y);
        acc.z = fmaf(ee[k], r23.x, acc.z);
        acc.w = fmaf(ee[k], r23.y, acc.w);
      }
    }
    for (; j < cnt; ++j) {
      int s0 = __shfl(sl, j, 16);
      float e0 = __shfl(ev, j, 16);
      uint2 rv = *(const uint2*)&h2h[(size_t)s0 * 32 + q * 2];
      float2 r01 = __half22float2(i2h((int)rv.x));
      float2 r23 = __half22float2(i2h((int)rv.y));
      se += e0;
      acc.x = fmaf(e0, r01.x, acc.x);
      acc.y = fmaf(e0, r01.y, acc.y);
      acc.z = fmaf(e0, r23.x, acc.z);
      acc.w = fmaf(e0, r23.y, acc.w);
    }
  }
  float4 o = {0, 0, 0, 0};
  if (act) {
    float inv = 1.f / se;
    o.x = fmaf(acc.x, inv, bias.x);
    o.y = fmaf(acc.y, inv, bias.y);
    o.z = fmaf(acc.z, inv, bias.z);
    o.w = fmaf(acc.w, inv, bias.w);
    unsigned p01 = (unsigned)h2i(__floats2half2_rn(o.x, o.y));
    unsigned p23 = (unsigned)h2i(__floats2half2_rn(o.z, o.w));
    *(uint2*)&v2h[(size_t)n * 32 + q * 2] = make_uint2(p01, p23);
  }
  __shared__ float4 reds[4][64], redq[4][64];
  reds[w][lane] = o;
  redq[w][lane] = make_float4(o.x * o.x, o.y * o.y, o.z * o.z, o.w * o.w);
  __syncthreads();
  if (t < 64) {
    int qq = t >> 2, ii = t & 3;
    float s = 0.f, sq = 0.f;
#pragma unroll
    for (int w2 = 0; w2 < 4; ++w2) {
#pragma unroll
      for (int g2 = 0; g2 < 4; ++g2) {
        s  += (&reds[w2][g2 * 16 + qq].x)[ii];
        sq += (&redq[w2][g2 * 16 + qq].x)[ii];
      }
    }
    int sl8 = (blockIdx.x & 7) * 128;
    atomicAdd(&stats[sl8 + t], s);
    atomicAdd(&stats[sl8 + 64 + t], sq);
  }
}

// ====== Final: out = relu(bn(v2h)) @ linW + linb, 2 nodes/wave, shared BN ======
__global__ __launch_bounds__(256) void k_out(
    const unsigned* __restrict__ v2h, const float* __restrict__ stats,
    const float* __restrict__ g2, const float* __restrict__ be2,
    const float* __restrict__ linW, const float* __restrict__ linb,
    float* __restrict__ out, int N, float rcpN)
{
  __shared__ float kc[64], sc[64], lw[64];
  int t = threadIdx.x;
  if (t < 64) {
    float su = 0.f, sq = 0.f;
#pragma unroll
    for (int s8 = 0; s8 < 8; ++s8) { su += stats[s8 * 128 + t]; sq += stats[s8 * 128 + 64 + t]; }
    float mu = su * rcpN;
    float var = sq * rcpN - mu * mu;
    float kk = g2[t] * rsqrtf(var + 1e-5f);
    kc[t] = kk; sc[t] = be2[t] - mu * kk; lw[t] = linW[t];
  }
  __syncthreads();
  int w = t >> 6, lane = t & 63, g = lane >> 5, q = lane & 31;
  int n = blockIdx.x * 8 + w * 2 + g;
  if (n >= N) return;
  unsigned uv = v2h[(size_t)n * 32 + q];
  float2 vf = __half22float2(i2h((int)uv));
  float h0 = fmaxf(vf.x * kc[2 * q] + sc[2 * q], 0.f);
  float h1 = fmaxf(vf.y * kc[2 * q + 1] + sc[2 * q + 1], 0.f);
  float p = fmaf(h0, lw[2 * q], h1 * lw[2 * q + 1]);
#pragma unroll
  for (int off = 16; off; off >>= 1) p += __shfl_xor(p, off, 32);
  if (q == 0) out[n] = p + linb[0];
}

extern "C" void kernel_launch(void* const* d_in, const int* in_sizes, int n_in,
                              void* d_out, int out_size, void* d_ws, size_t ws_size,
                              hipStream_t stream)
{
  const float* x    = (const float*)d_in[0];
  const int*   ei   = (const int*)d_in[1];
  const float* W1   = (const float*)d_in[2];
  const float* as1  = (const float*)d_in[3];
  const float* ad1  = (const float*)d_in[4];
  const float* b1   = (const float*)d_in[5];
  const float* g1   = (const float*)d_in[6];
  const float* be1  = (const float*)d_in[7];
  const float* W2   = (const float*)d_in[8];
  const float* as2  = (const float*)d_in[9];
  const float* ad2  = (const float*)d_in[10];
  const float* b2   = (const float*)d_in[11];
  const float* g2   = (const float*)d_in[12];
  const float* be2  = (const float*)d_in[13];
  const float* linW = (const float*)d_in[14];
  const float* linb = (const float*)d_in[15];
  float* out = (float*)d_out;

  int N = in_sizes[0] / 128;
  int E = in_sizes[1] / 2;
  int Etot = E + N;
  float rcpN = 1.f / (float)N;

  float* ws = (float*)d_ws;
  size_t o = 0;
  float* H1HF = ws + o; o += (size_t)N * 64;   // h1 fp16 (N x 128 halves); later h2h (N x 64 halves)
  float* V1HF = ws + o; o += (size_t)N * 64;   // v1 fp16; later v2h
  float* A1S  = ws + o; o += (size_t)N * 2;
  float* A1D  = ws + o; o += (size_t)N * 2;
  float* A2S  = ws + o; o += N;
  float* A2D  = ws + o; o += N;
  float* ST1  = ws + o; o += 8 * 256;          // 8-sliced layer-1 stats (zero region)
  float* ST2  = ws + o; o += 8 * 128;          // 8-sliced layer-2 stats
  int* ROWPTR = (int*)(ws + o); o += (size_t)N + 1;
  int* COL    = (int*)(ws + o); o += (size_t)Etot;
  int* DEG    = (int*)(ws + o); o += N;        // hist target, then scatter cursor
  int* PART   = (int*)(ws + o); o += 64;
  unsigned* H1H = (unsigned*)H1HF;
  unsigned* H2H = (unsigned*)H1HF;             // h2h aliases dead h1 region
  unsigned* V1H = (unsigned*)V1HF;
  unsigned* V2H = (unsigned*)V1HF;             // v2h aliases dead v1 region

  hipMemsetAsync(ST1, 0, 3072 * 4, stream);
  hipMemsetAsync(DEG, 0, (size_t)N * 4, stream);

  const int HB = 256;
  int gb = (N + 63) / 64;
  int ebk = (Etot + 255) / 256;
  int nb = (N + 1024) / 1024;                  // ceil((N+1)/1024) = 49 <= 64
  int ab1 = (N + 7) / 8;
  int ab2 = (N + 15) / 16;
  int ob  = (N + 7) / 8;

  k_pre<<<HB + gb, 256, 0, stream>>>(x, W1, as1, ad1, ei, DEG, H1H, A1S, A1D, N, E, Etot, HB);
  k_scan_blk<<<nb, 256, 0, stream>>>(DEG, ROWPTR, PART, N);
  k_add_off<<<nb, 256, 0, stream>>>(ROWPTR, PART, DEG, N, nb);
  k_scatter<<<ebk, 256, 0, stream>>>(ei, DEG, COL, E, Etot);
  k_agg1<<<ab1, 256, 0, stream>>>(ROWPTR, COL, H1H, A1S, A1D, b1, V1H, ST1, N);
  k_gemm2<<<gb, 256, 0, stream>>>(V1H, W2, ST1, g1, be1, as2, ad2, H2H, A2S, A2D, N, rcpN);
  k_agg2<<<ab2, 256, 0, stream>>>(ROWPTR, COL, H2H, A2S, A2D, b2, V2H, ST2, N);
  k_out<<<ob, 256, 0, stream>>>(V2H, ST2, g2, be2, linW, linb, out, N, rcpN);
}

// Round 11
// 231.557 us; speedup vs baseline: 1.5296x; 1.0601x over previous
//
#include <hip/hip_runtime.h>
#include <hip/hip_fp16.h>
#include <math.h>

#define LEAKY 0.2f
#define XPAD 136   // 128 + 8 halves row pad (16B-aligned rows, spread banks)

typedef _Float16 f16x8 __attribute__((ext_vector_type(8)));
typedef float f32x4 __attribute__((ext_vector_type(4)));

__device__ inline int h2i(__half2 h) { union { __half2 h; int i; } u; u.h = h; return u.i; }
__device__ inline __half2 i2h(int i) { union { __half2 h; int i; } u; u.i = i; return u.h; }

// ================= CSR build =================
__global__ __launch_bounds__(256) void k_hist(const int* __restrict__ ei,
                                              int* __restrict__ deg, int E, int Etot)
{
  int tid = blockIdx.x * 256 + threadIdx.x;
  if (tid >= Etot) return;
  int d = (tid < E) ? ei[E + tid] : tid - E;
  atomicAdd(&deg[d], 1);
}

__global__ __launch_bounds__(256) void k_scan_blk(const int* __restrict__ deg,
                                                  int* __restrict__ rowptr,
                                                  int* __restrict__ part, int N)
{
  __shared__ int ls[256];
  int t = threadIdx.x;
  int base = blockIdx.x * 1024 + t * 4;
  int d0 = (base     < N) ? deg[base]     : 0;
  int d1 = (base + 1 < N) ? deg[base + 1] : 0;
  int d2 = (base + 2 < N) ? deg[base + 2] : 0;
  int d3 = (base + 3 < N) ? deg[base + 3] : 0;
  int s = d0 + d1 + d2 + d3;
  ls[t] = s;
  __syncthreads();
  for (int off = 1; off < 256; off <<= 1) {
    int v = (t >= off) ? ls[t - off] : 0;
    __syncthreads();
    ls[t] += v;
    __syncthreads();
  }
  int excl = ls[t] - s;
  if (t == 255) part[blockIdx.x] = ls[255];
  if (base     <= N) rowptr[base]     = excl;
  if (base + 1 <= N) rowptr[base + 1] = excl + d0;
  if (base + 2 <= N) rowptr[base + 2] = excl + d0 + d1;
  if (base + 3 <= N) rowptr[base + 3] = excl + d0 + d1 + d2;
}

__global__ __launch_bounds__(256) void k_add_off(int* __restrict__ rowptr,
                                                 const int* __restrict__ part,
                                                 int* __restrict__ cur, int N, int nb)
{
  __shared__ int pexcl;
  int t = threadIdx.x;
  if (t < 64) {
    int v = (t < nb) ? part[t] : 0;
    int inc = v;
#pragma unroll
    for (int off = 1; off < 64; off <<= 1) {
      int u = __shfl_up(inc, off);
      if (t >= off) inc += u;
    }
    if (t == blockIdx.x) pexcl = inc - v;
  }
  __syncthreads();
  int p = pexcl;
  int base = blockIdx.x * 1024 + t * 4;
#pragma unroll
  for (int k = 0; k < 4; ++k) {
    int i = base + k;
    if (i <= N) {
      int v = rowptr[i] + p;
      rowptr[i] = v;
      if (i < N) cur[i] = v;
    }
  }
}

__global__ __launch_bounds__(256) void k_scatter(const int* __restrict__ ei,
                                                 int* __restrict__ cur,
                                                 int* __restrict__ colx, int E, int Etot)
{
  int tid = blockIdx.x * 256 + threadIdx.x;
  if (tid >= Etot) return;
  int s, d;
  if (tid < E) { s = ei[tid]; d = ei[E + tid]; }
  else { s = d = tid - E; }
  int pos = atomicAdd(&cur[d], 1);
  colx[pos] = s;
}

// ====== GEMM1 (MFMA): h1 = x @ W1 (N x 128 @ 128 x 128), fp16 out, fused att dots ======
// Per block: 64 rows, 4 waves; each wave one 16-row slab x 128 cols (8 col-tiles).
// mfma_f32_16x16x32_f16: A lane: row=l&15, k=(l>>4)*8+j; B: col=l&15, k=(l>>4)*8+j;
// C/D: col=l&15, row=(l>>4)*4+r  [m89-verified mapping].
__global__ __launch_bounds__(256) void k_gemm1(
    const float* __restrict__ x, const float* __restrict__ W,
    const float* __restrict__ att_s, const float* __restrict__ att_d,
    unsigned* __restrict__ h1h, float* __restrict__ a1s, float* __restrict__ a1d, int N)
{
  __shared__ __align__(16) _Float16 Xh[64 * XPAD];   // X tile fp16 (then reused for C)
  __shared__ __align__(16) _Float16 Wt[128 * XPAD];  // W^T fp16: [col][k]
  int t = threadIdx.x;
  const float4* W4 = (const float4*)W;
#pragma unroll
  for (int i = 0; i < 16; ++i) {
    int id = t + i * 256;
    int row = id >> 5, c0 = (id & 31) * 4;
    float4 wv = W4[id];
    Wt[(c0    ) * XPAD + row] = (_Float16)wv.x;
    Wt[(c0 + 1) * XPAD + row] = (_Float16)wv.y;
    Wt[(c0 + 2) * XPAD + row] = (_Float16)wv.z;
    Wt[(c0 + 3) * XPAD + row] = (_Float16)wv.w;
  }
  int row0 = blockIdx.x * 64;
  const float4* X4 = (const float4*)x;
#pragma unroll
  for (int i = 0; i < 8; ++i) {
    int id = t + i * 256;
    int r = id >> 5, c = id & 31;
    int gr = row0 + r;
    float4 v = (gr < N) ? X4[(size_t)gr * 32 + c] : make_float4(0.f, 0.f, 0.f, 0.f);
    unsigned p01 = (unsigned)h2i(__floats2half2_rn(v.x, v.y));
    unsigned p23 = (unsigned)h2i(__floats2half2_rn(v.z, v.w));
    *(uint2*)&Xh[r * XPAD + c * 4] = make_uint2(p01, p23);
  }
  __syncthreads();
  int w = t >> 6, l = t & 63;
  int m = l & 15, kg = l >> 4;
  f32x4 acc[8];
#pragma unroll
  for (int c = 0; c < 8; ++c) { acc[c][0] = 0.f; acc[c][1] = 0.f; acc[c][2] = 0.f; acc[c][3] = 0.f; }
#pragma unroll
  for (int ks = 0; ks < 4; ++ks) {
    f16x8 a = *(const f16x8*)&Xh[(w * 16 + m) * XPAD + ks * 32 + kg * 8];
#pragma unroll
    for (int c = 0; c < 8; ++c) {
      f16x8 b = *(const f16x8*)&Wt[(c * 16 + m) * XPAD + ks * 32 + kg * 8];
      acc[c] = __builtin_amdgcn_mfma_f32_16x16x32_f16(a, b, acc[c], 0, 0, 0);
    }
  }
  // C -> own 16-row slab of Xh (no cross-wave hazard: slabs disjoint)
#pragma unroll
  for (int c = 0; c < 8; ++c)
#pragma unroll
    for (int r = 0; r < 4; ++r)
      Xh[(w * 16 + kg * 4 + r) * XPAD + c * 16 + m] = (_Float16)acc[c][r];
  __syncthreads();
  // coalesced packed store + att dots (reduced over 16-lane head-halves)
#pragma unroll
  for (int i = 0; i < 8; ++i) {
    int id = t + i * 256;
    int r = id >> 5, c4 = id & 31;
    int gr = row0 + r;
    uint2 pk = *(const uint2*)&Xh[r * XPAD + c4 * 4];
    float2 v01 = __half22float2(i2h((int)pk.x));
    float2 v23 = __half22float2(i2h((int)pk.y));
    int col = c4 * 4;
    float4 asv = *(const float4*)&att_s[col];
    float4 adv = *(const float4*)&att_d[col];
    float ps = v01.x * asv.x + v01.y * asv.y + v23.x * asv.z + v23.y * asv.w;
    float pd = v01.x * adv.x + v01.y * adv.y + v23.x * adv.z + v23.y * adv.w;
    ps += __shfl_xor(ps, 1); ps += __shfl_xor(ps, 2); ps += __shfl_xor(ps, 4); ps += __shfl_xor(ps, 8);
    pd += __shfl_xor(pd, 1); pd += __shfl_xor(pd, 2); pd += __shfl_xor(pd, 4); pd += __shfl_xor(pd, 8);
    if (gr < N) {
      *(uint2*)&h1h[(size_t)gr * 64 + c4 * 2] = pk;
      if ((t & 15) == 0) { int h = (t >> 4) & 1; a1s[gr * 2 + h] = ps; a1d[gr * 2 + h] = pd; }
    }
  }
}

// ====== Aggregate layer 1: TWO nodes per wave (32-lane halves, uint2 feats) ======
__global__ __launch_bounds__(256) void k_agg1(
    const int* __restrict__ rowptr, const int* __restrict__ colx,
    const unsigned* __restrict__ h1h, const float* __restrict__ a1s,
    const float* __restrict__ a1d, const float* __restrict__ b1,
    unsigned* __restrict__ v1h, float* __restrict__ stats, int N)
{
  int t = threadIdx.x;
  int w = t >> 6, lane = t & 63;
  int g = lane >> 5, q = lane & 31;
  bool hi = q >= 16;
  int n = blockIdx.x * 8 + w * 2 + g;
  bool act = n < N;
  float4 bias = *(const float4*)&b1[q * 4];
  int start = 0, end = 0;
  float2 ad = make_float2(0.f, 0.f);
  if (act) { start = rowptr[n]; end = rowptr[n + 1]; ad = *(const float2*)&a1d[n * 2]; }
  float se = 0.f;
  float4 acc = {0, 0, 0, 0};
  for (int base = start; base < end; base += 32) {
    int cnt = end - base; if (cnt > 32) cnt = 32;
    int sl = 0, epk = 0;
    if (q < cnt) {
      sl = colx[base + q];
      float2 av = *(const float2*)&a1s[sl * 2];
      float x0 = av.x + ad.x, x1 = av.y + ad.y;
      x0 = (x0 > 0.f) ? x0 : LEAKY * x0;
      x1 = (x1 > 0.f) ? x1 : LEAKY * x1;
      epk = h2i(__floats2half2_rn(__expf(x0), __expf(x1)));
    }
    int j = 0;
    int lim16 = cnt & ~15;
    for (; j < lim16; j += 16) {
      int ss[16], ee[16];
#pragma unroll
      for (int k = 0; k < 16; ++k) { ss[k] = __shfl(sl, j + k, 32); ee[k] = __shfl(epk, j + k, 32); }
      uint2 rr[16];
#pragma unroll
      for (int k = 0; k < 16; ++k) rr[k] = *(const uint2*)&h1h[(size_t)ss[k] * 64 + q * 2];
#pragma unroll
      for (int k = 0; k < 16; ++k) {
        float2 ef = __half22float2(i2h(ee[k]));
        float wg = hi ? ef.y : ef.x;
        float2 r01 = __half22float2(i2h((int)rr[k].x));
        float2 r23 = __half22float2(i2h((int)rr[k].y));
        se += wg;
        acc.x = fmaf(wg, r01.x, acc.x);
        acc.y = fmaf(wg, r01.y, acc.y);
        acc.z = fmaf(wg, r23.x, acc.z);
        acc.w = fmaf(wg, r23.y, acc.w);
      }
    }
    int lim8 = cnt & ~7;
    for (; j < lim8; j += 8) {
      int ss[8], ee[8];
#pragma unroll
      for (int k = 0; k < 8; ++k) { ss[k] = __shfl(sl, j + k, 32); ee[k] = __shfl(epk, j + k, 32); }
      uint2 rr[8];
#pragma unroll
      for (int k = 0; k < 8; ++k) rr[k] = *(const uint2*)&h1h[(size_t)ss[k] * 64 + q * 2];
#pragma unroll
      for (int k = 0; k < 8; ++k) {
        float2 ef = __half22float2(i2h(ee[k]));
        float wg = hi ? ef.y : ef.x;
        float2 r01 = __half22float2(i2h((int)rr[k].x));
        float2 r23 = __half22float2(i2h((int)rr[k].y));
        se += wg;
        acc.x = fmaf(wg, r01.x, acc.x);
        acc.y = fmaf(wg, r01.y, acc.y);
        acc.z = fmaf(wg, r23.x, acc.z);
        acc.w = fmaf(wg, r23.y, acc.w);
      }
    }
    for (; j < cnt; ++j) {
      int s0 = __shfl(sl, j, 32), e0 = __shfl(epk, j, 32);
      float2 ef = __half22float2(i2h(e0));
      float wg = hi ? ef.y : ef.x;
      uint2 rv = *(const uint2*)&h1h[(size_t)s0 * 64 + q * 2];
      float2 r01 = __half22float2(i2h((int)rv.x));
      float2 r23 = __half22float2(i2h((int)rv.y));
      se += wg;
      acc.x = fmaf(wg, r01.x, acc.x);
      acc.y = fmaf(wg, r01.y, acc.y);
      acc.z = fmaf(wg, r23.x, acc.z);
      acc.w = fmaf(wg, r23.y, acc.w);
    }
  }
  float4 o = {0, 0, 0, 0};
  if (act) {
    float inv = 1.f / se;
    o.x = fmaf(acc.x, inv, bias.x);
    o.y = fmaf(acc.y, inv, bias.y);
    o.z = fmaf(acc.z, inv, bias.z);
    o.w = fmaf(acc.w, inv, bias.w);
    unsigned p01 = (unsigned)h2i(__floats2half2_rn(o.x, o.y));
    unsigned p23 = (unsigned)h2i(__floats2half2_rn(o.z, o.w));
    *(uint2*)&v1h[(size_t)n * 64 + q * 2] = make_uint2(p01, p23);
  }
  __shared__ float4 reds[4][64], redq[4][64];
  reds[w][lane] = o;
  redq[w][lane] = make_float4(o.x * o.x, o.y * o.y, o.z * o.z, o.w * o.w);
  __syncthreads();
  if (t < 128) {
    int qq = t >> 2, ii = t & 3;
    float s = 0.f, sq = 0.f;
#pragma unroll
    for (int w2 = 0; w2 < 4; ++w2) {
      s  += (&reds[w2][qq].x)[ii] + (&reds[w2][qq + 32].x)[ii];
      sq += (&redq[w2][qq].x)[ii] + (&redq[w2][qq + 32].x)[ii];
    }
    int sl8 = (blockIdx.x & 7) * 256;
    atomicAdd(&stats[sl8 + t], s);
    atomicAdd(&stats[sl8 + 128 + t], sq);
  }
}

// ====== GEMM2 (MFMA): h2 = relu(bn(v1h)) @ W2 (N x 128 @ 128 x 64), fp16 out ======
__global__ __launch_bounds__(256) void k_gemm2(
    const unsigned* __restrict__ v1h, const float* __restrict__ W2,
    const float* __restrict__ stats, const float* __restrict__ g1, const float* __restrict__ be1,
    const float* __restrict__ att_s, const float* __restrict__ att_d,
    unsigned* __restrict__ h2h, float* __restrict__ a2s, float* __restrict__ a2d,
    int N, float rcpN)
{
  __shared__ __align__(16) _Float16 Xh[64 * XPAD];   // BN+ReLU'd X tile; reused for C
  __shared__ __align__(16) _Float16 Wt[64 * XPAD];   // W2^T fp16: [col][k]
  __shared__ float kc[128], sc[128];
  int t = threadIdx.x;
  if (t < 128) {
    float su = 0.f, sq = 0.f;
#pragma unroll
    for (int s8 = 0; s8 < 8; ++s8) { su += stats[s8 * 256 + t]; sq += stats[s8 * 256 + 128 + t]; }
    float mu = su * rcpN;
    float var = sq * rcpN - mu * mu;
    float kk = g1[t] * rsqrtf(var + 1e-5f);
    kc[t] = kk; sc[t] = be1[t] - mu * kk;
  }
  const float4* W4 = (const float4*)W2;
#pragma unroll
  for (int i = 0; i < 8; ++i) {
    int id = t + i * 256;               // 2048 float4: row=id>>4 (128), c0=(id&15)*4 (64 cols)
    int row = id >> 4, c0 = (id & 15) * 4;
    float4 wv = W4[id];
    Wt[(c0    ) * XPAD + row] = (_Float16)wv.x;
    Wt[(c0 + 1) * XPAD + row] = (_Float16)wv.y;
    Wt[(c0 + 2) * XPAD + row] = (_Float16)wv.z;
    Wt[(c0 + 3) * XPAD + row] = (_Float16)wv.w;
  }
  __syncthreads();
  int row0 = blockIdx.x * 64;
#pragma unroll
  for (int i = 0; i < 8; ++i) {
    int id = t + i * 256;
    int r = id >> 5, c4 = id & 31;
    int gr = row0 + r;
    uint2 pv = (gr < N) ? *(const uint2*)&v1h[(size_t)gr * 64 + c4 * 2] : make_uint2(0, 0);
    float2 a01 = __half22float2(i2h((int)pv.x));
    float2 a23 = __half22float2(i2h((int)pv.y));
    int f0 = c4 * 4;
    float o0 = fmaxf(a01.x * kc[f0]     + sc[f0],     0.f);
    float o1 = fmaxf(a01.y * kc[f0 + 1] + sc[f0 + 1], 0.f);
    float o2 = fmaxf(a23.x * kc[f0 + 2] + sc[f0 + 2], 0.f);
    float o3 = fmaxf(a23.y * kc[f0 + 3] + sc[f0 + 3], 0.f);
    unsigned p01 = (unsigned)h2i(__floats2half2_rn(o0, o1));
    unsigned p23 = (unsigned)h2i(__floats2half2_rn(o2, o3));
    *(uint2*)&Xh[r * XPAD + c4 * 4] = make_uint2(p01, p23);
  }
  __syncthreads();
  int w = t >> 6, l = t & 63;
  int m = l & 15, kg = l >> 4;
  f32x4 acc[4];
#pragma unroll
  for (int c = 0; c < 4; ++c) { acc[c][0] = 0.f; acc[c][1] = 0.f; acc[c][2] = 0.f; acc[c][3] = 0.f; }
#pragma unroll
  for (int ks = 0; ks < 4; ++ks) {
    f16x8 a = *(const f16x8*)&Xh[(w * 16 + m) * XPAD + ks * 32 + kg * 8];
#pragma unroll
    for (int c = 0; c < 4; ++c) {
      f16x8 b = *(const f16x8*)&Wt[(c * 16 + m) * XPAD + ks * 32 + kg * 8];
      acc[c] = __builtin_amdgcn_mfma_f32_16x16x32_f16(a, b, acc[c], 0, 0, 0);
    }
  }
#pragma unroll
  for (int c = 0; c < 4; ++c)
#pragma unroll
    for (int r = 0; r < 4; ++r)
      Xh[(w * 16 + kg * 4 + r) * XPAD + c * 16 + m] = (_Float16)acc[c][r];
  __syncthreads();
#pragma unroll
  for (int i = 0; i < 4; ++i) {
    int id = t + i * 256;               // 1024: r=id>>4 (64 rows), c4=id&15 (16 groups of 4 cols)
    int r = id >> 4, c4 = id & 15;
    int gr = row0 + r;
    uint2 pk = *(const uint2*)&Xh[r * XPAD + c4 * 4];
    float2 v01 = __half22float2(i2h((int)pk.x));
    float2 v23 = __half22float2(i2h((int)pk.y));
    int col = c4 * 4;
    float4 asv = *(const float4*)&att_s[col];
    float4 adv = *(const float4*)&att_d[col];
    float ps = v01.x * asv.x + v01.y * asv.y + v23.x * asv.z + v23.y * asv.w;
    float pd = v01.x * adv.x + v01.y * adv.y + v23.x * adv.z + v23.y * adv.w;
    ps += __shfl_xor(ps, 1); ps += __shfl_xor(ps, 2); ps += __shfl_xor(ps, 4); ps += __shfl_xor(ps, 8);
    pd += __shfl_xor(pd, 1); pd += __shfl_xor(pd, 2); pd += __shfl_xor(pd, 4); pd += __shfl_xor(pd, 8);
    if (gr < N) {
      *(uint2*)&h2h[(size_t)gr * 32 + c4 * 2] = pk;
      if ((t & 15) == 0) { a2s[gr] = ps; a2d[gr] = pd; }
    }
  }
}

// ====== Aggregate layer 2: FOUR nodes per wave (16-lane groups, uint2 feats) ======
__global__ __launch_bounds__(256) void k_agg2(
    const int* __restrict__ rowptr, const int* __restrict__ colx,
    const unsigned* __restrict__ h2h, const float* __restrict__ a2s,
    const float* __restrict__ a2d, const float* __restrict__ b2,
    unsigned* __restrict__ v2h, float* __restrict__ stats, int N)
{
  int t = threadIdx.x;
  int w = t >> 6, lane = t & 63;
  int g = lane >> 4, q = lane & 15;
  int n = blockIdx.x * 16 + w * 4 + g;
  bool act = n < N;
  float4 bias = *(const float4*)&b2[q * 4];
  int start = 0, end = 0;
  float ad = 0.f;
  if (act) { start = rowptr[n]; end = rowptr[n + 1]; ad = a2d[n]; }
  float se = 0.f;
  float4 acc = {0, 0, 0, 0};
  for (int base = start; base < end; base += 16) {
    int cnt = end - base; if (cnt > 16) cnt = 16;
    int sl = 0; float ev = 0.f;
    if (q < cnt) {
      sl = colx[base + q];
      float av = a2s[sl] + ad;
      av = (av > 0.f) ? av : LEAKY * av;
      ev = __expf(av);
    }
    int j = 0;
    if (cnt == 16) {
      int ss[16]; float ee[16];
#pragma unroll
      for (int k = 0; k < 16; ++k) { ss[k] = __shfl(sl, k, 16); ee[k] = __shfl(ev, k, 16); }
      uint2 rr[16];
#pragma unroll
      for (int k = 0; k < 16; ++k) rr[k] = *(const uint2*)&h2h[(size_t)ss[k] * 32 + q * 2];
#pragma unroll
      for (int k = 0; k < 16; ++k) {
        float2 r01 = __half22float2(i2h((int)rr[k].x));
        float2 r23 = __half22float2(i2h((int)rr[k].y));
        se += ee[k];
        acc.x = fmaf(ee[k], r01.x, acc.x);
        acc.y = fmaf(ee[k], r01.y, acc.y);
        acc.z = fmaf(ee[k], r23.x, acc.z);
        acc.w = fmaf(ee[k], r23.y, acc.w);
      }
      j = 16;
    }
    int lim8 = cnt & ~7;
    for (; j < lim8; j += 8) {
      int ss[8]; float ee[8];
#pragma unroll
      for (int k = 0; k < 8; ++k) { ss[k] = __shfl(sl, j + k, 16); ee[k] = __shfl(ev, j + k, 16); }
      uint2 rr[8];
#pragma unroll
      for (int k = 0; k < 8; ++k) rr[k] = *(const uint2*)&h2h[(size_t)ss[k] * 32 + q * 2];
#pragma unroll
      for (int k = 0; k < 8; ++k) {
        float2 r01 = __half22float2(i2h((int)rr[k].x));
        float2 r23 = __half22float2(i2h((int)rr[k].y));
        se += ee[k];
        acc.x = fmaf(ee[k], r01.x, acc.x);
        acc.y = fmaf(ee[k], r01.y, acc.y);
        acc.z = fmaf(ee[k], r23.x, acc.z);
        acc.w = fmaf(ee[k], r23.y, acc.w);
      }
    }
    for (; j < cnt; ++j) {
      int s0 = __shfl(sl, j, 16);
      float e0 = __shfl(ev, j, 16);
      uint2 rv = *(const uint2*)&h2h[(size_t)s0 * 32 + q * 2];
      float2 r01 = __half22float2(i2h((int)rv.x));
      float2 r23 = __half22float2(i2h((int)rv.y));
      se += e0;
      acc.x = fmaf(e0, r01.x, acc.x);
      acc.y = fmaf(e0, r01.y, acc.y);
      acc.z = fmaf(e0, r23.x, acc.z);
      acc.w = fmaf(e0, r23.y, acc.w);
    }
  }
  float4 o = {0, 0, 0, 0};
  if (act) {
    float inv = 1.f / se;
    o.x = fmaf(acc.x, inv, bias.x);
    o.y = fmaf(acc.y, inv, bias.y);
    o.z = fmaf(acc.z, inv, bias.z);
    o.w = fmaf(acc.w, inv, bias.w);
    unsigned p01 = (unsigned)h2i(__floats2half2_rn(o.x, o.y));
    unsigned p23 = (unsigned)h2i(__floats2half2_rn(o.z, o.w));
    *(uint2*)&v2h[(size_t)n * 32 + q * 2] = make_uint2(p01, p23);
  }
  __shared__ float4 reds[4][64], redq[4][64];
  reds[w][lane] = o;
  redq[w][lane] = make_float4(o.x * o.x, o.y * o.y, o.z * o.z, o.w * o.w);
  __syncthreads();
  if (t < 64) {
    int qq = t >> 2, ii = t & 3;
    float s = 0.f, sq = 0.f;
#pragma unroll
    for (int w2 = 0; w2 < 4; ++w2) {
#pragma unroll
      for (int g2 = 0; g2 < 4; ++g2) {
        s  += (&reds[w2][g2 * 16 + qq].x)[ii];
        sq += (&redq[w2][g2 * 16 + qq].x)[ii];
      }
    }
    int sl8 = (blockIdx.x & 7) * 128;
    atomicAdd(&stats[sl8 + t], s);
    atomicAdd(&stats[sl8 + 64 + t], sq);
  }
}

// ====== Final: out = relu(bn(v2h)) @ linW + linb, 2 nodes/wave, shared BN ======
__global__ __launch_bounds__(256) void k_out(
    const unsigned* __restrict__ v2h, const float* __restrict__ stats,
    const float* __restrict__ g2, const float* __restrict__ be2,
    const float* __restrict__ linW, const float* __restrict__ linb,
    float* __restrict__ out, int N, float rcpN)
{
  __shared__ float kc[64], sc[64], lw[64];
  int t = threadIdx.x;
  if (t < 64) {
    float su = 0.f, sq = 0.f;
#pragma unroll
    for (int s8 = 0; s8 < 8; ++s8) { su += stats[s8 * 128 + t]; sq += stats[s8 * 128 + 64 + t]; }
    float mu = su * rcpN;
    float var = sq * rcpN - mu * mu;
    float kk = g2[t] * rsqrtf(var + 1e-5f);
    kc[t] = kk; sc[t] = be2[t] - mu * kk; lw[t] = linW[t];
  }
  __syncthreads();
  int w = t >> 6, lane = t & 63, g = lane >> 5, q = lane & 31;
  int n = blockIdx.x * 8 + w * 2 + g;
  if (n >= N) return;
  unsigned uv = v2h[(size_t)n * 32 + q];
  float2 vf = __half22float2(i2h((int)uv));
  float h0 = fmaxf(vf.x * kc[2 * q] + sc[2 * q], 0.f);
  float h1 = fmaxf(vf.y * kc[2 * q + 1] + sc[2 * q + 1], 0.f);
  float p = fmaf(h0, lw[2 * q], h1 * lw[2 * q + 1]);
#pragma unroll
  for (int off = 16; off; off >>= 1) p += __shfl_xor(p, off, 32);
  if (q == 0) out[n] = p + linb[0];
}

extern "C" void kernel_launch(void* const* d_in, const int* in_sizes, int n_in,
                              void* d_out, int out_size, void* d_ws, size_t ws_size,
                              hipStream_t stream)
{
  const float* x    = (const float*)d_in[0];
  const int*   ei   = (const int*)d_in[1];
  const float* W1   = (const float*)d_in[2];
  const float* as1  = (const float*)d_in[3];
  const float* ad1  = (const float*)d_in[4];
  const float* b1   = (const float*)d_in[5];
  const float* g1   = (const float*)d_in[6];
  const float* be1  = (const float*)d_in[7];
  const float* W2   = (const float*)d_in[8];
  const float* as2  = (const float*)d_in[9];
  const float* ad2  = (const float*)d_in[10];
  const float* b2   = (const float*)d_in[11];
  const float* g2   = (const float*)d_in[12];
  const float* be2  = (const float*)d_in[13];
  const float* linW = (const float*)d_in[14];
  const float* linb = (const float*)d_in[15];
  float* out = (float*)d_out;

  int N = in_sizes[0] / 128;
  int E = in_sizes[1] / 2;
  int Etot = E + N;
  float rcpN = 1.f / (float)N;

  float* ws = (float*)d_ws;
  size_t o = 0;
  float* H1HF = ws + o; o += (size_t)N * 64;   // h1 fp16 (N x 128 halves); later h2h (N x 64 halves)
  float* V1HF = ws + o; o += (size_t)N * 64;   // v1 fp16; later v2h
  float* A1S  = ws + o; o += (size_t)N * 2;
  float* A1D  = ws + o; o += (size_t)N * 2;
  float* A2S  = ws + o; o += N;
  float* A2D  = ws + o; o += N;
  float* ST1  = ws + o; o += 8 * 256;          // 8-sliced layer-1 stats (zero region)
  float* ST2  = ws + o; o += 8 * 128;          // 8-sliced layer-2 stats
  int* ROWPTR = (int*)(ws + o); o += (size_t)N + 1;
  int* COL    = (int*)(ws + o); o += (size_t)Etot;
  int* DEG    = (int*)(ws + o); o += N;        // hist target, then scatter cursor
  int* PART   = (int*)(ws + o); o += 64;
  unsigned* H1H = (unsigned*)H1HF;
  unsigned* H2H = (unsigned*)H1HF;             // h2h aliases dead h1 region
  unsigned* V1H = (unsigned*)V1HF;
  unsigned* V2H = (unsigned*)V1HF;             // v2h aliases dead v1 region

  hipMemsetAsync(ST1, 0, 3072 * 4, stream);
  hipMemsetAsync(DEG, 0, (size_t)N * 4, stream);

  int gb = (N + 63) / 64;
  int ebk = (Etot + 255) / 256;
  int nb = (N + 1024) / 1024;                  // ceil((N+1)/1024) = 49 <= 64
  int ab1 = (N + 7) / 8;
  int ab2 = (N + 15) / 16;
  int ob  = (N + 7) / 8;

  k_hist<<<ebk, 256, 0, stream>>>(ei, DEG, E, Etot);
  k_scan_blk<<<nb, 256, 0, stream>>>(DEG, ROWPTR, PART, N);
  k_add_off<<<nb, 256, 0, stream>>>(ROWPTR, PART, DEG, N, nb);
  k_scatter<<<ebk, 256, 0, stream>>>(ei, DEG, COL, E, Etot);
  k_gemm1<<<gb, 256, 0, stream>>>(x, W1, as1, ad1, H1H, A1S, A1D, N);
  k_agg1<<<ab1, 256, 0, stream>>>(ROWPTR, COL, H1H, A1S, A1D, b1, V1H, ST1, N);
  k_gemm2<<<gb, 256, 0, stream>>>(V1H, W2, ST1, g1, be1, as2, ad2, H2H, A2S, A2D, N, rcpN);
  k_agg2<<<ab2, 256, 0, stream>>>(ROWPTR, COL, H2H, A2S, A2D, b2, V2H, ST2, N);
  k_out<<<ob, 256, 0, stream>>>(V2H, ST2, g2, be2, linW, linb, out, N, rcpN);
}

// Round 12
// 170.824 us; speedup vs baseline: 2.0734x; 1.3555x over previous
//
#include <hip/hip_runtime.h>
#include <hip/hip_fp16.h>
#include <math.h>

#define LEAKY 0.2f
#define XPAD 136   // 128 + 8 halves row pad
#define MAXB 512   // max dst-buckets (R=128 nodes each; N<=65536)

typedef _Float16 f16x8 __attribute__((ext_vector_type(8)));
typedef float f32x4 __attribute__((ext_vector_type(4)));

__device__ inline int h2i(__half2 h) { union { __half2 h; int i; } u; u.h = h; return u.i; }
__device__ inline __half2 i2h(int i) { union { __half2 h; int i; } u; u.i = i; return u.h; }

// ====== CSR build: bucketed partition (no global scatter atomics) ======
// Buckets: b = dst >> 7 (128 nodes each). Self-loops handled analytically.

__global__ __launch_bounds__(256) void k_bhist(const int* __restrict__ ei,
                                               int* __restrict__ gbcnt, int E, int PB)
{
  __shared__ int lh[MAXB];
  int t = threadIdx.x;
  for (int i = t; i < PB; i += 256) lh[i] = 0;
  __syncthreads();
  int base = blockIdx.x * 2048;
#pragma unroll
  for (int k = 0; k < 8; ++k) {
    int idx = base + t + k * 256;
    if (idx < E) atomicAdd(&lh[ei[E + idx] >> 7], 1);
  }
  __syncthreads();
  for (int i = t; i < PB; i += 256) if (lh[i]) atomicAdd(&gbcnt[i], lh[i]);
}

__global__ __launch_bounds__(512) void k_bscan(const int* __restrict__ gbcnt,
                                               int* __restrict__ pbase,
                                               int* __restrict__ gcur, int PB)
{
  __shared__ int ls[512];
  int t = threadIdx.x;
  int v = (t < PB) ? gbcnt[t] : 0;
  ls[t] = v;
  __syncthreads();
  for (int off = 1; off < 512; off <<= 1) {
    int u = (t >= off) ? ls[t - off] : 0;
    __syncthreads();
    ls[t] += u;
    __syncthreads();
  }
  int excl = ls[t] - v;
  if (t <= PB) pbase[t] = excl;
  if (t < PB) gcur[t] = excl;
}

// partition: per-block LDS counts -> bulk reserve -> contiguous runs of (s,d)
__global__ __launch_bounds__(256) void k_part(const int* __restrict__ ei,
                                              int* __restrict__ gcur,
                                              int2* __restrict__ pairs, int E, int PB)
{
  __shared__ int lcnt[MAXB], lbase[MAXB];
  int t = threadIdx.x;
  for (int i = t; i < PB; i += 256) lcnt[i] = 0;
  __syncthreads();
  int base = blockIdx.x * 4096;
  int lp[16];
#pragma unroll
  for (int k = 0; k < 16; ++k) {
    int idx = base + t + k * 256;
    int pk = -1;
    if (idx < E) {
      int b = ei[E + idx] >> 7;
      int p = atomicAdd(&lcnt[b], 1);
      pk = (p << 10) | b;            // p < 4096 (12b), b < 512 (10b... shift 10 safe)
    }
    lp[k] = pk;
  }
  __syncthreads();
  for (int b = t; b < PB; b += 256) lbase[b] = atomicAdd(&gcur[b], lcnt[b]);
  __syncthreads();
#pragma unroll
  for (int k = 0; k < 16; ++k) {
    if (lp[k] >= 0) {
      int idx = base + t + k * 256;
      int b = lp[k] & 1023, p = lp[k] >> 10;
      pairs[lbase[b] + p] = make_int2(ei[idx], ei[E + idx]);
    }
  }
}

// per-bucket: local deg (+1 self) -> local scan = rowptr -> LDS-cursor scatter
__global__ __launch_bounds__(256) void k_fine(const int2* __restrict__ pairs,
                                              const int* __restrict__ pbase,
                                              int* __restrict__ rowptr,
                                              int* __restrict__ colx, int N)
{
  __shared__ int ldeg[128], lcur[128];
  int b = blockIdx.x, t = threadIdx.x;
  int nbase = b << 7;
  int nbn = N - nbase; if (nbn > 128) nbn = 128;
  if (t < 128) ldeg[t] = (t < nbn) ? 1 : 0;   // self-loop pre-counted
  __syncthreads();
  int e0 = pbase[b], e1 = pbase[b + 1];
  for (int e = e0 + t; e < e1; e += 256) atomicAdd(&ldeg[pairs[e].y - nbase], 1);
  __syncthreads();
  int myv = (t < 128) ? ldeg[t] : 0;
  for (int off = 1; off < 128; off <<= 1) {
    int u = (t < 128 && t >= off) ? ldeg[t - off] : 0;
    __syncthreads();
    if (t < 128) ldeg[t] += u;
    __syncthreads();
  }
  int colx0 = e0 + nbase;                      // pbase[b] + (#self-loops before bucket)
  if (t < 128) {
    int excl = ldeg[t] - myv;
    lcur[t] = colx0 + excl;
    int idx = nbase + t;
    if (idx <= N) rowptr[idx] = colx0 + excl;
  }
  __syncthreads();
  for (int e = e0 + t; e < e1; e += 256) {
    int2 p = pairs[e];
    int pos = atomicAdd(&lcur[p.y - nbase], 1);
    colx[pos] = p.x;
  }
  if (t < nbn) {
    int pos = atomicAdd(&lcur[t], 1);
    colx[pos] = nbase + t;                     // self-loop entry
  }
}

// ====== GEMM1 (MFMA): h1 = x @ W1 (N x 128 @ 128 x 128), fp16 out, fused att dots ======
__global__ __launch_bounds__(256) void k_gemm1(
    const float* __restrict__ x, const float* __restrict__ W,
    const float* __restrict__ att_s, const float* __restrict__ att_d,
    unsigned* __restrict__ h1h, float* __restrict__ a1s, float* __restrict__ a1d, int N)
{
  __shared__ __align__(16) _Float16 Xh[64 * XPAD];
  __shared__ __align__(16) _Float16 Wt[128 * XPAD];
  int t = threadIdx.x;
  const float4* W4 = (const float4*)W;
#pragma unroll
  for (int i = 0; i < 16; ++i) {
    int id = t + i * 256;
    int row = id >> 5, c0 = (id & 31) * 4;
    float4 wv = W4[id];
    Wt[(c0    ) * XPAD + row] = (_Float16)wv.x;
    Wt[(c0 + 1) * XPAD + row] = (_Float16)wv.y;
    Wt[(c0 + 2) * XPAD + row] = (_Float16)wv.z;
    Wt[(c0 + 3) * XPAD + row] = (_Float16)wv.w;
  }
  int row0 = blockIdx.x * 64;
  const float4* X4 = (const float4*)x;
#pragma unroll
  for (int i = 0; i < 8; ++i) {
    int id = t + i * 256;
    int r = id >> 5, c = id & 31;
    int gr = row0 + r;
    float4 v = (gr < N) ? X4[(size_t)gr * 32 + c] : make_float4(0.f, 0.f, 0.f, 0.f);
    unsigned p01 = (unsigned)h2i(__floats2half2_rn(v.x, v.y));
    unsigned p23 = (unsigned)h2i(__floats2half2_rn(v.z, v.w));
    *(uint2*)&Xh[r * XPAD + c * 4] = make_uint2(p01, p23);
  }
  __syncthreads();
  int w = t >> 6, l = t & 63;
  int m = l & 15, kg = l >> 4;
  f32x4 acc[8];
#pragma unroll
  for (int c = 0; c < 8; ++c) { acc[c][0] = 0.f; acc[c][1] = 0.f; acc[c][2] = 0.f; acc[c][3] = 0.f; }
#pragma unroll
  for (int ks = 0; ks < 4; ++ks) {
    f16x8 a = *(const f16x8*)&Xh[(w * 16 + m) * XPAD + ks * 32 + kg * 8];
#pragma unroll
    for (int c = 0; c < 8; ++c) {
      f16x8 bfr = *(const f16x8*)&Wt[(c * 16 + m) * XPAD + ks * 32 + kg * 8];
      acc[c] = __builtin_amdgcn_mfma_f32_16x16x32_f16(a, bfr, acc[c], 0, 0, 0);
    }
  }
#pragma unroll
  for (int c = 0; c < 8; ++c)
#pragma unroll
    for (int r = 0; r < 4; ++r)
      Xh[(w * 16 + kg * 4 + r) * XPAD + c * 16 + m] = (_Float16)acc[c][r];
  __syncthreads();
#pragma unroll
  for (int i = 0; i < 8; ++i) {
    int id = t + i * 256;
    int r = id >> 5, c4 = id & 31;
    int gr = row0 + r;
    uint2 pk = *(const uint2*)&Xh[r * XPAD + c4 * 4];
    float2 v01 = __half22float2(i2h((int)pk.x));
    float2 v23 = __half22float2(i2h((int)pk.y));
    int col = c4 * 4;
    float4 asv = *(const float4*)&att_s[col];
    float4 adv = *(const float4*)&att_d[col];
    float ps = v01.x * asv.x + v01.y * asv.y + v23.x * asv.z + v23.y * asv.w;
    float pd = v01.x * adv.x + v01.y * adv.y + v23.x * adv.z + v23.y * adv.w;
    ps += __shfl_xor(ps, 1); ps += __shfl_xor(ps, 2); ps += __shfl_xor(ps, 4); ps += __shfl_xor(ps, 8);
    pd += __shfl_xor(pd, 1); pd += __shfl_xor(pd, 2); pd += __shfl_xor(pd, 4); pd += __shfl_xor(pd, 8);
    if (gr < N) {
      *(uint2*)&h1h[(size_t)gr * 64 + c4 * 2] = pk;
      if ((t & 15) == 0) { int h = (t >> 4) & 1; a1s[gr * 2 + h] = ps; a1d[gr * 2 + h] = pd; }
    }
  }
}

// ====== Aggregate layer 1: TWO nodes per wave (32-lane halves, uint2 feats) ======
__global__ __launch_bounds__(256) void k_agg1(
    const int* __restrict__ rowptr, const int* __restrict__ colx,
    const unsigned* __restrict__ h1h, const float* __restrict__ a1s,
    const float* __restrict__ a1d, const float* __restrict__ b1,
    unsigned* __restrict__ v1h, float* __restrict__ stats, int N)
{
  int t = threadIdx.x;
  int w = t >> 6, lane = t & 63;
  int g = lane >> 5, q = lane & 31;
  bool hi = q >= 16;
  int n = blockIdx.x * 8 + w * 2 + g;
  bool act = n < N;
  float4 bias = *(const float4*)&b1[q * 4];
  int start = 0, end = 0;
  float2 ad = make_float2(0.f, 0.f);
  if (act) { start = rowptr[n]; end = rowptr[n + 1]; ad = *(const float2*)&a1d[n * 2]; }
  float se = 0.f;
  float4 acc = {0, 0, 0, 0};
  for (int base = start; base < end; base += 32) {
    int cnt = end - base; if (cnt > 32) cnt = 32;
    int sl = 0, epk = 0;
    if (q < cnt) {
      sl = colx[base + q];
      float2 av = *(const float2*)&a1s[sl * 2];
      float x0 = av.x + ad.x, x1 = av.y + ad.y;
      x0 = (x0 > 0.f) ? x0 : LEAKY * x0;
      x1 = (x1 > 0.f) ? x1 : LEAKY * x1;
      epk = h2i(__floats2half2_rn(__expf(x0), __expf(x1)));
    }
    int j = 0;
    int lim16 = cnt & ~15;
    for (; j < lim16; j += 16) {
      int ss[16], ee[16];
#pragma unroll
      for (int k = 0; k < 16; ++k) { ss[k] = __shfl(sl, j + k, 32); ee[k] = __shfl(epk, j + k, 32); }
      uint2 rr[16];
#pragma unroll
      for (int k = 0; k < 16; ++k) rr[k] = *(const uint2*)&h1h[(size_t)ss[k] * 64 + q * 2];
#pragma unroll
      for (int k = 0; k < 16; ++k) {
        float2 ef = __half22float2(i2h(ee[k]));
        float wg = hi ? ef.y : ef.x;
        float2 r01 = __half22float2(i2h((int)rr[k].x));
        float2 r23 = __half22float2(i2h((int)rr[k].y));
        se += wg;
        acc.x = fmaf(wg, r01.x, acc.x);
        acc.y = fmaf(wg, r01.y, acc.y);
        acc.z = fmaf(wg, r23.x, acc.z);
        acc.w = fmaf(wg, r23.y, acc.w);
      }
    }
    int lim8 = cnt & ~7;
    for (; j < lim8; j += 8) {
      int ss[8], ee[8];
#pragma unroll
      for (int k = 0; k < 8; ++k) { ss[k] = __shfl(sl, j + k, 32); ee[k] = __shfl(epk, j + k, 32); }
      uint2 rr[8];
#pragma unroll
      for (int k = 0; k < 8; ++k) rr[k] = *(const uint2*)&h1h[(size_t)ss[k] * 64 + q * 2];
#pragma unroll
      for (int k = 0; k < 8; ++k) {
        float2 ef = __half22float2(i2h(ee[k]));
        float wg = hi ? ef.y : ef.x;
        float2 r01 = __half22float2(i2h((int)rr[k].x));
        float2 r23 = __half22float2(i2h((int)rr[k].y));
        se += wg;
        acc.x = fmaf(wg, r01.x, acc.x);
        acc.y = fmaf(wg, r01.y, acc.y);
        acc.z = fmaf(wg, r23.x, acc.z);
        acc.w = fmaf(wg, r23.y, acc.w);
      }
    }
    for (; j < cnt; ++j) {
      int s0 = __shfl(sl, j, 32), e0 = __shfl(epk, j, 32);
      float2 ef = __half22float2(i2h(e0));
      float wg = hi ? ef.y : ef.x;
      uint2 rv = *(const uint2*)&h1h[(size_t)s0 * 64 + q * 2];
      float2 r01 = __half22float2(i2h((int)rv.x));
      float2 r23 = __half22float2(i2h((int)rv.y));
      se += wg;
      acc.x = fmaf(wg, r01.x, acc.x);
      acc.y = fmaf(wg, r01.y, acc.y);
      acc.z = fmaf(wg, r23.x, acc.z);
      acc.w = fmaf(wg, r23.y, acc.w);
    }
  }
  float4 o = {0, 0, 0, 0};
  if (act) {
    float inv = 1.f / se;
    o.x = fmaf(acc.x, inv, bias.x);
    o.y = fmaf(acc.y, inv, bias.y);
    o.z = fmaf(acc.z, inv, bias.z);
    o.w = fmaf(acc.w, inv, bias.w);
    unsigned p01 = (unsigned)h2i(__floats2half2_rn(o.x, o.y));
    unsigned p23 = (unsigned)h2i(__floats2half2_rn(o.z, o.w));
    *(uint2*)&v1h[(size_t)n * 64 + q * 2] = make_uint2(p01, p23);
  }
  __shared__ float4 reds[4][64], redq[4][64];
  reds[w][lane] = o;
  redq[w][lane] = make_float4(o.x * o.x, o.y * o.y, o.z * o.z, o.w * o.w);
  __syncthreads();
  if (t < 128) {
    int qq = t >> 2, ii = t & 3;
    float s = 0.f, sq = 0.f;
#pragma unroll
    for (int w2 = 0; w2 < 4; ++w2) {
      s  += (&reds[w2][qq].x)[ii] + (&reds[w2][qq + 32].x)[ii];
      sq += (&redq[w2][qq].x)[ii] + (&redq[w2][qq + 32].x)[ii];
    }
    int sl8 = (blockIdx.x & 7) * 256;
    atomicAdd(&stats[sl8 + t], s);
    atomicAdd(&stats[sl8 + 128 + t], sq);
  }
}

// ====== GEMM2 (MFMA): h2 = relu(bn(v1h)) @ W2 (N x 128 @ 128 x 64), fp16 out ======
__global__ __launch_bounds__(256) void k_gemm2(
    const unsigned* __restrict__ v1h, const float* __restrict__ W2,
    const float* __restrict__ stats, const float* __restrict__ g1, const float* __restrict__ be1,
    const float* __restrict__ att_s, const float* __restrict__ att_d,
    unsigned* __restrict__ h2h, float* __restrict__ a2s, float* __restrict__ a2d,
    int N, float rcpN)
{
  __shared__ __align__(16) _Float16 Xh[64 * XPAD];
  __shared__ __align__(16) _Float16 Wt[64 * XPAD];
  __shared__ float kc[128], sc[128];
  int t = threadIdx.x;
  if (t < 128) {
    float su = 0.f, sq = 0.f;
#pragma unroll
    for (int s8 = 0; s8 < 8; ++s8) { su += stats[s8 * 256 + t]; sq += stats[s8 * 256 + 128 + t]; }
    float mu = su * rcpN;
    float var = sq * rcpN - mu * mu;
    float kk = g1[t] * rsqrtf(var + 1e-5f);
    kc[t] = kk; sc[t] = be1[t] - mu * kk;
  }
  const float4* W4 = (const float4*)W2;
#pragma unroll
  for (int i = 0; i < 8; ++i) {
    int id = t + i * 256;
    int row = id >> 4, c0 = (id & 15) * 4;
    float4 wv = W4[id];
    Wt[(c0    ) * XPAD + row] = (_Float16)wv.x;
    Wt[(c0 + 1) * XPAD + row] = (_Float16)wv.y;
    Wt[(c0 + 2) * XPAD + row] = (_Float16)wv.z;
    Wt[(c0 + 3) * XPAD + row] = (_Float16)wv.w;
  }
  __syncthreads();
  int row0 = blockIdx.x * 64;
#pragma unroll
  for (int i = 0; i < 8; ++i) {
    int id = t + i * 256;
    int r = id >> 5, c4 = id & 31;
    int gr = row0 + r;
    uint2 pv = (gr < N) ? *(const uint2*)&v1h[(size_t)gr * 64 + c4 * 2] : make_uint2(0, 0);
    float2 a01 = __half22float2(i2h((int)pv.x));
    float2 a23 = __half22float2(i2h((int)pv.y));
    int f0 = c4 * 4;
    float o0 = fmaxf(a01.x * kc[f0]     + sc[f0],     0.f);
    float o1 = fmaxf(a01.y * kc[f0 + 1] + sc[f0 + 1], 0.f);
    float o2 = fmaxf(a23.x * kc[f0 + 2] + sc[f0 + 2], 0.f);
    float o3 = fmaxf(a23.y * kc[f0 + 3] + sc[f0 + 3], 0.f);
    unsigned p01 = (unsigned)h2i(__floats2half2_rn(o0, o1));
    unsigned p23 = (unsigned)h2i(__floats2half2_rn(o2, o3));
    *(uint2*)&Xh[r * XPAD + c4 * 4] = make_uint2(p01, p23);
  }
  __syncthreads();
  int w = t >> 6, l = t & 63;
  int m = l & 15, kg = l >> 4;
  f32x4 acc[4];
#pragma unroll
  for (int c = 0; c < 4; ++c) { acc[c][0] = 0.f; acc[c][1] = 0.f; acc[c][2] = 0.f; acc[c][3] = 0.f; }
#pragma unroll
  for (int ks = 0; ks < 4; ++ks) {
    f16x8 a = *(const f16x8*)&Xh[(w * 16 + m) * XPAD + ks * 32 + kg * 8];
#pragma unroll
    for (int c = 0; c < 4; ++c) {
      f16x8 bfr = *(const f16x8*)&Wt[(c * 16 + m) * XPAD + ks * 32 + kg * 8];
      acc[c] = __builtin_amdgcn_mfma_f32_16x16x32_f16(a, bfr, acc[c], 0, 0, 0);
    }
  }
#pragma unroll
  for (int c = 0; c < 4; ++c)
#pragma unroll
    for (int r = 0; r < 4; ++r)
      Xh[(w * 16 + kg * 4 + r) * XPAD + c * 16 + m] = (_Float16)acc[c][r];
  __syncthreads();
#pragma unroll
  for (int i = 0; i < 4; ++i) {
    int id = t + i * 256;
    int r = id >> 4, c4 = id & 15;
    int gr = row0 + r;
    uint2 pk = *(const uint2*)&Xh[r * XPAD + c4 * 4];
    float2 v01 = __half22float2(i2h((int)pk.x));
    float2 v23 = __half22float2(i2h((int)pk.y));
    int col = c4 * 4;
    float4 asv = *(const float4*)&att_s[col];
    float4 adv = *(const float4*)&att_d[col];
    float ps = v01.x * asv.x + v01.y * asv.y + v23.x * asv.z + v23.y * asv.w;
    float pd = v01.x * adv.x + v01.y * adv.y + v23.x * adv.z + v23.y * adv.w;
    ps += __shfl_xor(ps, 1); ps += __shfl_xor(ps, 2); ps += __shfl_xor(ps, 4); ps += __shfl_xor(ps, 8);
    pd += __shfl_xor(pd, 1); pd += __shfl_xor(pd, 2); pd += __shfl_xor(pd, 4); pd += __shfl_xor(pd, 8);
    if (gr < N) {
      *(uint2*)&h2h[(size_t)gr * 32 + c4 * 2] = pk;
      if ((t & 15) == 0) { a2s[gr] = ps; a2d[gr] = pd; }
    }
  }
}

// ====== Aggregate layer 2: FOUR nodes per wave (16-lane groups, uint2 feats) ======
__global__ __launch_bounds__(256) void k_agg2(
    const int* __restrict__ rowptr, const int* __restrict__ colx,
    const unsigned* __restrict__ h2h, const float* __restrict__ a2s,
    const float* __restrict__ a2d, const float* __restrict__ b2,
    unsigned* __restrict__ v2h, float* __restrict__ stats, int N)
{
  int t = threadIdx.x;
  int w = t >> 6, lane = t & 63;
  int g = lane >> 4, q = lane & 15;
  int n = blockIdx.x * 16 + w * 4 + g;
  bool act = n < N;
  float4 bias = *(const float4*)&b2[q * 4];
  int start = 0, end = 0;
  float ad = 0.f;
  if (act) { start = rowptr[n]; end = rowptr[n + 1]; ad = a2d[n]; }
  float se = 0.f;
  float4 acc = {0, 0, 0, 0};
  for (int base = start; base < end; base += 16) {
    int cnt = end - base; if (cnt > 16) cnt = 16;
    int sl = 0; float ev = 0.f;
    if (q < cnt) {
      sl = colx[base + q];
      float av = a2s[sl] + ad;
      av = (av > 0.f) ? av : LEAKY * av;
      ev = __expf(av);
    }
    int j = 0;
    if (cnt == 16) {
      int ss[16]; float ee[16];
#pragma unroll
      for (int k = 0; k < 16; ++k) { ss[k] = __shfl(sl, k, 16); ee[k] = __shfl(ev, k, 16); }
      uint2 rr[16];
#pragma unroll
      for (int k = 0; k < 16; ++k) rr[k] = *(const uint2*)&h2h[(size_t)ss[k] * 32 + q * 2];
#pragma unroll
      for (int k = 0; k < 16; ++k) {
        float2 r01 = __half22float2(i2h((int)rr[k].x));
        float2 r23 = __half22float2(i2h((int)rr[k].y));
        se += ee[k];
        acc.x = fmaf(ee[k], r01.x, acc.x);
        acc.y = fmaf(ee[k], r01.y, acc.y);
        acc.z = fmaf(ee[k], r23.x, acc.z);
        acc.w = fmaf(ee[k], r23.y, acc.w);
      }
      j = 16;
    }
    int lim8 = cnt & ~7;
    for (; j < lim8; j += 8) {
      int ss[8]; float ee[8];
#pragma unroll
      for (int k = 0; k < 8; ++k) { ss[k] = __shfl(sl, j + k, 16); ee[k] = __shfl(ev, j + k, 16); }
      uint2 rr[8];
#pragma unroll
      for (int k = 0; k < 8; ++k) rr[k] = *(const uint2*)&h2h[(size_t)ss[k] * 32 + q * 2];
#pragma unroll
      for (int k = 0; k < 8; ++k) {
        float2 r01 = __half22float2(i2h((int)rr[k].x));
        float2 r23 = __half22float2(i2h((int)rr[k].y));
        se += ee[k];
        acc.x = fmaf(ee[k], r01.x, acc.x);
        acc.y = fmaf(ee[k], r01.y, acc.y);
        acc.z = fmaf(ee[k], r23.x, acc.z);
        acc.w = fmaf(ee[k], r23.y, acc.w);
      }
    }
    for (; j < cnt; ++j) {
      int s0 = __shfl(sl, j, 16);
      float e0 = __shfl(ev, j, 16);
      uint2 rv = *(const uint2*)&h2h[(size_t)s0 * 32 + q * 2];
      float2 r01 = __half22float2(i2h((int)rv.x));
      float2 r23 = __half22float2(i2h((int)rv.y));
      se += e0;
      acc.x = fmaf(e0, r01.x, acc.x);
      acc.y = fmaf(e0, r01.y, acc.y);
      acc.z = fmaf(e0, r23.x, acc.z);
      acc.w = fmaf(e0, r23.y, acc.w);
    }
  }
  float4 o = {0, 0, 0, 0};
  if (act) {
    float inv = 1.f / se;
    o.x = fmaf(acc.x, inv, bias.x);
    o.y = fmaf(acc.y, inv, bias.y);
    o.z = fmaf(acc.z, inv, bias.z);
    o.w = fmaf(acc.w, inv, bias.w);
    unsigned p01 = (unsigned)h2i(__floats2half2_rn(o.x, o.y));
    unsigned p23 = (unsigned)h2i(__floats2half2_rn(o.z, o.w));
    *(uint2*)&v2h[(size_t)n * 32 + q * 2] = make_uint2(p01, p23);
  }
  __shared__ float4 reds[4][64], redq[4][64];
  reds[w][lane] = o;
  redq[w][lane] = make_float4(o.x * o.x, o.y * o.y, o.z * o.z, o.w * o.w);
  __syncthreads();
  if (t < 64) {
    int qq = t >> 2, ii = t & 3;
    float s = 0.f, sq = 0.f;
#pragma unroll
    for (int w2 = 0; w2 < 4; ++w2) {
#pragma unroll
      for (int g2 = 0; g2 < 4; ++g2) {
        s  += (&reds[w2][g2 * 16 + qq].x)[ii];
        sq += (&redq[w2][g2 * 16 + qq].x)[ii];
      }
    }
    int sl8 = (blockIdx.x & 7) * 128;
    atomicAdd(&stats[sl8 + t], s);
    atomicAdd(&stats[sl8 + 64 + t], sq);
  }
}

// ====== Final: out = relu(bn(v2h)) @ linW + linb, 2 nodes/wave, shared BN ======
__global__ __launch_bounds__(256) void k_out(
    const unsigned* __restrict__ v2h, const float* __restrict__ stats,
    const float* __restrict__ g2, const float* __restrict__ be2,
    const float* __restrict__ linW, const float* __restrict__ linb,
    float* __restrict__ out, int N, float rcpN)
{
  __shared__ float kc[64], sc[64], lw[64];
  int t = threadIdx.x;
  if (t < 64) {
    float su = 0.f, sq = 0.f;
#pragma unroll
    for (int s8 = 0; s8 < 8; ++s8) { su += stats[s8 * 128 + t]; sq += stats[s8 * 128 + 64 + t]; }
    float mu = su * rcpN;
    float var = sq * rcpN - mu * mu;
    float kk = g2[t] * rsqrtf(var + 1e-5f);
    kc[t] = kk; sc[t] = be2[t] - mu * kk; lw[t] = linW[t];
  }
  __syncthreads();
  int w = t >> 6, lane = t & 63, g = lane >> 5, q = lane & 31;
  int n = blockIdx.x * 8 + w * 2 + g;
  if (n >= N) return;
  unsigned uv = v2h[(size_t)n * 32 + q];
  float2 vf = __half22float2(i2h((int)uv));
  float h0 = fmaxf(vf.x * kc[2 * q] + sc[2 * q], 0.f);
  float h1 = fmaxf(vf.y * kc[2 * q + 1] + sc[2 * q + 1], 0.f);
  float p = fmaf(h0, lw[2 * q], h1 * lw[2 * q + 1]);
#pragma unroll
  for (int off = 16; off; off >>= 1) p += __shfl_xor(p, off, 32);
  if (q == 0) out[n] = p + linb[0];
}

extern "C" void kernel_launch(void* const* d_in, const int* in_sizes, int n_in,
                              void* d_out, int out_size, void* d_ws, size_t ws_size,
                              hipStream_t stream)
{
  const float* x    = (const float*)d_in[0];
  const int*   ei   = (const int*)d_in[1];
  const float* W1   = (const float*)d_in[2];
  const float* as1  = (const float*)d_in[3];
  const float* ad1  = (const float*)d_in[4];
  const float* b1   = (const float*)d_in[5];
  const float* g1   = (const float*)d_in[6];
  const float* be1  = (const float*)d_in[7];
  const float* W2   = (const float*)d_in[8];
  const float* as2  = (const float*)d_in[9];
  const float* ad2  = (const float*)d_in[10];
  const float* b2   = (const float*)d_in[11];
  const float* g2   = (const float*)d_in[12];
  const float* be2  = (const float*)d_in[13];
  const float* linW = (const float*)d_in[14];
  const float* linb = (const float*)d_in[15];
  float* out = (float*)d_out;

  int N = in_sizes[0] / 128;
  int E = in_sizes[1] / 2;
  int Etot = E + N;
  float rcpN = 1.f / (float)N;
  int PB = (N + 127) / 128;                    // dst buckets (<= MAXB)

  float* ws = (float*)d_ws;
  size_t o = 0;
  float* H1HF = ws + o; o += (size_t)N * 64;   // h1 fp16; later h2h
  float* V1HF = ws + o; o += (size_t)N * 64;   // v1 fp16; later v2h
  float* A1S  = ws + o; o += (size_t)N * 2;
  float* A1D  = ws + o; o += (size_t)N * 2;
  float* A2S  = ws + o; o += N;
  float* A2D  = ws + o; o += N;
  float* ST1  = ws + o; o += 8 * 256;          // zero region start
  float* ST2  = ws + o; o += 8 * 128;
  int* GBCNT  = (int*)(ws + o); o += MAXB;     // zero region end
  int* PBASE  = (int*)(ws + o); o += MAXB + 1;
  int* GCUR   = (int*)(ws + o); o += MAXB;
  int* ROWPTR = (int*)(ws + o); o += (size_t)N + 1;
  int* COL    = (int*)(ws + o); o += (size_t)Etot;
  int2* PAIRS = (int2*)(ws + o); o += (size_t)E * 2;
  unsigned* H1H = (unsigned*)H1HF;
  unsigned* H2H = (unsigned*)H1HF;
  unsigned* V1H = (unsigned*)V1HF;
  unsigned* V2H = (unsigned*)V1HF;

  hipMemsetAsync(ST1, 0, (3072 + MAXB) * 4, stream);

  int gb  = (N + 63) / 64;
  int bh  = (E + 2047) / 2048;
  int pt  = (E + 4095) / 4096;
  int ab1 = (N + 7) / 8;
  int ab2 = (N + 15) / 16;
  int ob  = (N + 7) / 8;

  k_bhist<<<bh, 256, 0, stream>>>(ei, GBCNT, E, PB);
  k_bscan<<<1, 512, 0, stream>>>(GBCNT, PBASE, GCUR, PB);
  k_part<<<pt, 256, 0, stream>>>(ei, GCUR, PAIRS, E, PB);
  k_fine<<<PB, 256, 0, stream>>>(PAIRS, PBASE, ROWPTR, COL, N);
  k_gemm1<<<gb, 256, 0, stream>>>(x, W1, as1, ad1, H1H, A1S, A1D, N);
  k_agg1<<<ab1, 256, 0, stream>>>(ROWPTR, COL, H1H, A1S, A1D, b1, V1H, ST1, N);
  k_gemm2<<<gb, 256, 0, stream>>>(V1H, W2, ST1, g1, be1, as2, ad2, H2H, A2S, A2D, N, rcpN);
  k_agg2<<<ab2, 256, 0, stream>>>(ROWPTR, COL, H2H, A2S, A2D, b2, V2H, ST2, N);
  k_out<<<ob, 256, 0, stream>>>(V2H, ST2, g2, be2, linW, linb, out, N, rcpN);
}